// Round 1
// baseline (1089.892 us; speedup 1.0000x reference)
//
#include <hip/hip_runtime.h>
#include <math.h>

#define BN    2456
#define LSEQ  12
#define DM    128
#define DFF   128
#define DTR   32
#define DST   16
#define NODES 307
#define NBAT  8

// ---------------- weight transpose: [R][C] -> [C][R] per expert ----------------
__global__ void k_transpose(const float* __restrict__ in_w, const float* __restrict__ x_w,
                            const float* __restrict__ out_w, const float* __restrict__ dt_w,
                            float* __restrict__ in_wT, float* __restrict__ x_wT,
                            float* __restrict__ out_wT, float* __restrict__ dt_wT) {
    int which = blockIdx.y;
    int idx = blockIdx.x * blockDim.x + threadIdx.x;
    const float* src; float* dst; int R, C;
    if (which == 0)      { src = in_w;  dst = in_wT;  R = 256; C = 128; }
    else if (which == 1) { src = x_w;   dst = x_wT;   R = 192; C = 128; }
    else if (which == 2) { src = out_w; dst = out_wT; R = 128; C = 128; }
    else                 { src = dt_w;  dst = dt_wT;  R = 128; C = 32;  }
    int per = R * C;
    if (idx >= 4 * per) return;
    int e = idx / per, rem = idx - e * per;
    int r = rem / C, c = rem - r * C;
    dst[e * per + c * R + r] = src[idx];
}

// ---------------- block reductions over 128 threads (2 waves) ----------------
template <int N>
__device__ __forceinline__ void red_sum128(float* v, float* sred, int tid) {
#pragma unroll
    for (int off = 32; off; off >>= 1)
#pragma unroll
        for (int i = 0; i < N; ++i) v[i] += __shfl_xor(v[i], off, 64);
    if ((tid & 63) == 0) {
#pragma unroll
        for (int i = 0; i < N; ++i) sred[(tid >> 6) * N + i] = v[i];
    }
    __syncthreads();
#pragma unroll
    for (int i = 0; i < N; ++i) v[i] = sred[i] + sred[N + i];
    __syncthreads();
}

template <int N>
__device__ __forceinline__ void red_max128(float* v, float* sred, int tid) {
#pragma unroll
    for (int off = 32; off; off >>= 1)
#pragma unroll
        for (int i = 0; i < N; ++i) v[i] = fmaxf(v[i], __shfl_xor(v[i], off, 64));
    if ((tid & 63) == 0) {
#pragma unroll
        for (int i = 0; i < N; ++i) sred[(tid >> 6) * N + i] = v[i];
    }
    __syncthreads();
#pragma unroll
    for (int i = 0; i < N; ++i) v[i] = fmaxf(sred[i], sred[N + i]);
    __syncthreads();
}

// ---------------- K1: rmsnorm + frequency gating ----------------
// grid: BN blocks x 128 threads (thread = d)
__global__ __launch_bounds__(128)
void k_freq(const float* __restrict__ xcur, const float* __restrict__ norm_w,
            const float* __restrict__ fw_r, const float* __restrict__ fw_i,
            float* __restrict__ xn, float* __restrict__ xfreq, int e) {
    __shared__ float s_c[24], s_s[24];
    __shared__ float s_wr[133], s_wi[133];
    __shared__ float sred[24];
    const int row = blockIdx.x, tid = threadIdx.x;

    if (tid < 24) {
        float sv, cv;
        sincosf(6.283185307179586f * (float)tid / 24.0f, &sv, &cv);
        s_c[tid] = cv; s_s[tid] = sv;
    }
    for (int i = tid; i < 133; i += 128) { s_wr[i] = fw_r[e * 133 + i]; s_wi[i] = fw_i[e * 133 + i]; }

    const float* xp = xcur + (size_t)row * (LSEQ * DM) + tid;
    float xv[12], v[12];
#pragma unroll
    for (int l = 0; l < 12; ++l) { xv[l] = xp[l * DM]; v[l] = xv[l] * xv[l]; }
    __syncthreads();
    red_sum128<12>(v, sred, tid);

    const float nw = norm_w[e * DM + tid];
    float xnr[12];
#pragma unroll
    for (int l = 0; l < 12; ++l)
        xnr[l] = xv[l] * rsqrtf(v[l] * (1.0f / 128.0f) + 1e-5f) * nw;

    float* xnp = xn + (size_t)row * (LSEQ * DM) + tid;
#pragma unroll
    for (int l = 0; l < 12; ++l) xnp[l * DM] = xnr[l];

    // DFTs: f (n=12, 7 bins), fp (n=24 padded, 13 bins). angle = -2*pi*t/24
    float fr[7], fi[7], fpr[13], fpi[13];
#pragma unroll
    for (int o2 = 0; o2 < 7; ++o2) { fr[o2] = 0.f; fi[o2] = 0.f; }
#pragma unroll
    for (int k = 0; k < 13; ++k) { fpr[k] = 0.f; fpi[k] = 0.f; }
#pragma unroll
    for (int l = 0; l < 12; ++l) {
#pragma unroll
        for (int o2 = 0; o2 < 7; ++o2) {
            const int t = (2 * o2 * l) % 24;
            fr[o2] += xnr[l] * s_c[t];
            fi[o2] -= xnr[l] * s_s[t];
        }
#pragma unroll
        for (int k = 0; k < 13; ++k) {
            const int t = (k * l) % 24;
            fpr[k] += xnr[l] * s_c[t];
            fpi[k] -= xnr[l] * s_s[t];
        }
    }

    // top-6 of (f.re+U)^2+(f.im+U)^2, descending (7-elem unrolled bubble)
    float a7[7];
#pragma unroll
    for (int o2 = 0; o2 < 7; ++o2) {
        float ar = fr[o2] + 1e-6f, ai = fi[o2] + 1e-6f;
        a7[o2] = ar * ar + ai * ai;
    }
#pragma unroll
    for (int pss = 0; pss < 6; ++pss)
#pragma unroll
        for (int j = 0; j < 6; ++j) {
            float hi = fmaxf(a7[j], a7[j + 1]);
            float lo = fminf(a7[j], a7[j + 1]);
            a7[j] = hi; a7[j + 1] = lo;
        }

    // freq_proj[o] = sum_k cat[k]*W[o][k];  p = |freq_proj|^2
    float p7[7];
#pragma unroll
    for (int o2 = 0; o2 < 7; ++o2) {
        float pr = 0.f, pi = 0.f;
#pragma unroll
        for (int k = 0; k < 13; ++k) {
            const float wr = s_wr[o2 * 19 + k], wi = s_wi[o2 * 19 + k];
            pr += fpr[k] * wr - fpi[k] * wi;
            pi += fpr[k] * wi + fpi[k] * wr;
        }
#pragma unroll
        for (int k = 0; k < 6; ++k) {
            const float wr = s_wr[o2 * 19 + 13 + k], wi = s_wi[o2 * 19 + 13 + k];
            pr += a7[k] * wr;
            pi += a7[k] * wi;
        }
        p7[o2] = pr * pr + pi * pi;
    }

    // softmax over d (threads), per o
    float m7[7], ex[7], sm[7];
#pragma unroll
    for (int o2 = 0; o2 < 7; ++o2) m7[o2] = p7[o2];
    red_max128<7>(m7, sred, tid);
#pragma unroll
    for (int o2 = 0; o2 < 7; ++o2) { ex[o2] = expf(p7[o2] - m7[o2]); sm[o2] = ex[o2]; }
    red_sum128<7>(sm, sred, tid);

    float gr[7], gi[7];
#pragma unroll
    for (int o2 = 0; o2 < 7; ++o2) {
        const float wf = ex[o2] / sm[o2];
        gr[o2] = wf * fr[o2];
        gi[o2] = wf * fi[o2];
    }

    // irfft, n=12: X[l] = (g0 + (-1)^l g6 + 2*sum_{o=1..5}(gr*cos - gi*sin)) / 12
    float* xfp = xfreq + (size_t)row * (LSEQ * DM) + tid;
#pragma unroll
    for (int l = 0; l < 12; ++l) {
        float val = gr[0] + ((l & 1) ? -gr[6] : gr[6]);
#pragma unroll
        for (int o2 = 1; o2 < 6; ++o2) {
            const int t = (2 * o2 * l) % 24;
            val += 2.0f * (gr[o2] * s_c[t] - gi[o2] * s_s[t]);
        }
        xfp[l * DM] = val * (1.0f / 12.0f);
    }
}

// ---------------- K2: in_proj + silu split ----------------
// grid: BN x 256 (thread = output col j of 256)
__global__ __launch_bounds__(256)
void k_inproj(const float* __restrict__ xn, const float* __restrict__ in_wT,
              const float* __restrict__ in_b, float* __restrict__ xs,
              float* __restrict__ sz, int e) {
    __shared__ float s_xn[1536];
    const int row = blockIdx.x, tid = threadIdx.x;
    const float* src = xn + (size_t)row * 1536;
#pragma unroll
    for (int i = 0; i < 6; ++i) s_xn[tid + i * 256] = src[tid + i * 256];
    __syncthreads();

    const float* W = in_wT + e * 32768 + tid;
    const float b = in_b[e * 256 + tid];
    float acc[12];
#pragma unroll
    for (int l = 0; l < 12; ++l) acc[l] = b;
    for (int d = 0; d < 128; d += 4) {
        const float w0 = W[(d + 0) * 256], w1 = W[(d + 1) * 256];
        const float w2 = W[(d + 2) * 256], w3 = W[(d + 3) * 256];
#pragma unroll
        for (int l = 0; l < 12; ++l) {
            const float4 xv = *(const float4*)&s_xn[l * 128 + d];
            acc[l] = fmaf(xv.x, w0, acc[l]);
            acc[l] = fmaf(xv.y, w1, acc[l]);
            acc[l] = fmaf(xv.z, w2, acc[l]);
            acc[l] = fmaf(xv.w, w3, acc[l]);
        }
    }
    float* dst = (tid < 128) ? (xs + (size_t)row * 1536 + tid)
                             : (sz + (size_t)row * 1536 + (tid - 128));
#pragma unroll
    for (int l = 0; l < 12; ++l) {
        const float vz = acc[l];
        dst[l * 128] = vz / (1.0f + expf(-vz));
    }
}

// ---------------- K3: x_proj + dt_proj + softplus ----------------
// grid: BN x 192 (thread = output col of 192)
__global__ __launch_bounds__(192)
void k_xproj(const float* __restrict__ xs, const float* __restrict__ x_wT,
             const float* __restrict__ dt_wT, const float* __restrict__ dt_b,
             float* __restrict__ dbcd, float* __restrict__ delta, int e) {
    __shared__ float s_xs[1536];
    __shared__ float s_dr[12 * 32];
    const int row = blockIdx.x, tid = threadIdx.x;
    const float* src = xs + (size_t)row * 1536;
    for (int i = tid; i < 1536; i += 192) s_xs[i] = src[i];
    __syncthreads();

    const float* W = x_wT + e * 24576 + tid;
    float acc[12];
#pragma unroll
    for (int l = 0; l < 12; ++l) acc[l] = 0.f;
    for (int d = 0; d < 128; d += 4) {
        const float w0 = W[(d + 0) * 192], w1 = W[(d + 1) * 192];
        const float w2 = W[(d + 2) * 192], w3 = W[(d + 3) * 192];
#pragma unroll
        for (int l = 0; l < 12; ++l) {
            const float4 xv = *(const float4*)&s_xs[l * 128 + d];
            acc[l] = fmaf(xv.x, w0, acc[l]);
            acc[l] = fmaf(xv.y, w1, acc[l]);
            acc[l] = fmaf(xv.z, w2, acc[l]);
            acc[l] = fmaf(xv.w, w3, acc[l]);
        }
    }
    float* dst = dbcd + (size_t)row * 2304 + tid;
#pragma unroll
    for (int l = 0; l < 12; ++l) {
        dst[l * 192] = acc[l];
        if (tid < 32) s_dr[l * 32 + tid] = acc[l];
    }
    __syncthreads();

    if (tid < 128) {
        const float* DW = dt_wT + e * 4096 + tid;
        const float db = dt_b[e * 128 + tid];
        float dacc[12];
#pragma unroll
        for (int l = 0; l < 12; ++l) dacc[l] = db;
        for (int r = 0; r < 32; ++r) {
            const float w = DW[r * 128];
#pragma unroll
            for (int l = 0; l < 12; ++l) dacc[l] += s_dr[l * 32 + r] * w;
        }
        float* dd = delta + (size_t)row * 1536 + tid;
#pragma unroll
        for (int l = 0; l < 12; ++l) {
            const float x = dacc[l];
            dd[l * 128] = fmaxf(x, 0.f) + log1pf(expf(-fabsf(x)));  // softplus
        }
    }
}

// ---------------- K4: graph mixing ----------------
// grid: (96 = b*12+l, 10 node-chunks of 32) x 128 (thread = output col a)
__global__ __launch_bounds__(128)
void k_graphmix(const float* __restrict__ delta, const float* __restrict__ graph,
                float* __restrict__ dmix) {
    const int bl = blockIdx.x;
    const int b = bl / 12, l = bl % 12;
    const int n0 = blockIdx.y * 32;
    const int count = min(32, NODES - n0);
    const int tid = threadIdx.x;
    __shared__ float s_d[32 * 128];
    for (int i = tid; i < 32 * 128; i += 128) {
        const int r = i >> 7, c = i & 127;
        s_d[i] = (r < count) ? delta[((size_t)(b * NODES + n0 + r) * 12 + l) * 128 + c] : 0.0f;
    }
    __syncthreads();

    const float* G = graph + ((size_t)(b * 12 + l) * 128) * 128 + tid;
    float acc[32];
#pragma unroll
    for (int r = 0; r < 32; ++r) acc[r] = 0.f;
    for (int d = 0; d < 128; d += 4) {
        const float g0 = G[(d + 0) * 128], g1 = G[(d + 1) * 128];
        const float g2 = G[(d + 2) * 128], g3 = G[(d + 3) * 128];
#pragma unroll
        for (int r = 0; r < 32; ++r) {
            const float4 dv = *(const float4*)&s_d[r * 128 + d];
            acc[r] = fmaf(dv.x, g0, acc[r]);
            acc[r] = fmaf(dv.y, g1, acc[r]);
            acc[r] = fmaf(dv.z, g2, acc[r]);
            acc[r] = fmaf(dv.w, g3, acc[r]);
        }
    }
#pragma unroll
    for (int r = 0; r < 32; ++r) {
        if (r < count)
            dmix[((size_t)(b * NODES + n0 + r) * 12 + l) * 128 + tid] = acc[r];
    }
}

// ---------------- K5: SSM scan + gate + out_proj + residual (+final silu) ----------------
// grid: BN x 128 (thread = d for scan, = m for out_proj)
__global__ __launch_bounds__(128)
void k_ssm(const float* __restrict__ dmix, const float* __restrict__ xs,
           const float* __restrict__ szb, const float* __restrict__ xfreq,
           const float* __restrict__ dbcd, const float* __restrict__ A_log,
           const float* __restrict__ out_wT, const float* __restrict__ out_b,
           const float* __restrict__ blk_w, const float* __restrict__ blk_b,
           const float* __restrict__ xprev, float* __restrict__ xout,
           int e, int last) {
    __shared__ float s_dm[1536], s_xs[1536], s_out[1536];
    __shared__ float s_B[192], s_C[192];
    const int row = blockIdx.x, tid = threadIdx.x;
    const float* dmp = dmix + (size_t)row * 1536;
    const float* xsp = xs + (size_t)row * 1536;
#pragma unroll
    for (int i = 0; i < 12; ++i) {
        s_dm[tid + i * 128] = dmp[tid + i * 128];
        s_xs[tid + i * 128] = xsp[tid + i * 128];
    }
    const float* bc = dbcd + (size_t)row * 2304;
    for (int i = tid; i < 192; i += 128) {
        const int l = i >> 4, s = i & 15;
        s_B[i] = bc[l * 192 + 32 + s];
        s_C[i] = bc[l * 192 + 48 + s];
    }
    float As[16];
#pragma unroll
    for (int s = 0; s < 16; ++s) As[s] = -expf(A_log[e * 16 + s]);

    float dpv[12], szv[12], xfv[12];
    const float* szp = szb + (size_t)row * 1536 + tid;
    const float* xfp = xfreq + (size_t)row * 1536 + tid;
#pragma unroll
    for (int l = 0; l < 12; ++l) {
        dpv[l] = bc[l * 192 + 64 + tid];
        szv[l] = szp[l * 128];
        xfv[l] = xfp[l * 128];
    }
    __syncthreads();

    float h[16];
#pragma unroll
    for (int s = 0; s < 16; ++s) h[s] = 0.f;
#pragma unroll
    for (int l = 0; l < 12; ++l) {
        const float dl = s_dm[l * 128 + tid];
        const float xv = s_xs[l * 128 + tid];
        float y = 0.f;
#pragma unroll
        for (int s = 0; s < 16; ++s) {
            h[s] = expf(dl * As[s]) * h[s] + dl * s_B[l * 16 + s] * xv;
            y += h[s] * s_C[l * 16 + s];
        }
        y += dpv[l] * xv;
        s_out[l * 128 + tid] = y * szv[l] * xfv[l];
    }
    __syncthreads();

    // out_proj: thread = output m
    const float* W = out_wT + e * 16384 + tid;
    float facc[12];
#pragma unroll
    for (int l = 0; l < 12; ++l) facc[l] = 0.f;
    for (int d = 0; d < 128; d += 4) {
        const float w0 = W[(d + 0) * 128], w1 = W[(d + 1) * 128];
        const float w2 = W[(d + 2) * 128], w3 = W[(d + 3) * 128];
#pragma unroll
        for (int l = 0; l < 12; ++l) {
            const float4 ov = *(const float4*)&s_out[l * 128 + d];
            facc[l] = fmaf(ov.x, w0, facc[l]);
            facc[l] = fmaf(ov.y, w1, facc[l]);
            facc[l] = fmaf(ov.z, w2, facc[l]);
            facc[l] = fmaf(ov.w, w3, facc[l]);
        }
    }
    const float ob = out_b[e * 128 + tid];
    const float bw = blk_w[e], bb = blk_b[e];
    const float* xpp = xprev + (size_t)row * 1536 + tid;
    float* xop = xout + (size_t)row * 1536 + tid;
#pragma unroll
    for (int l = 0; l < 12; ++l) {
        const float r = bw * (facc[l] + ob) + bb;
        float vv = xpp[l * 128] + r;
        if (last) vv = vv / (1.0f + expf(-vv));
        xop[l * 128] = vv;
    }
}

extern "C" void kernel_launch(void* const* d_in, const int* in_sizes, int n_in,
                              void* d_out, int out_size, void* d_ws, size_t ws_size,
                              hipStream_t stream) {
    (void)in_sizes; (void)n_in; (void)out_size; (void)ws_size;
    const float* x_in   = (const float*)d_in[0];
    const float* graph  = (const float*)d_in[1];
    const float* in_w   = (const float*)d_in[2];
    const float* in_b   = (const float*)d_in[3];
    const float* x_w    = (const float*)d_in[4];
    const float* dt_w   = (const float*)d_in[5];
    const float* dt_b   = (const float*)d_in[6];
    const float* A_log  = (const float*)d_in[7];
    const float* out_w  = (const float*)d_in[8];
    const float* out_b  = (const float*)d_in[9];
    const float* fw_r   = (const float*)d_in[10];
    const float* fw_i   = (const float*)d_in[11];
    const float* norm_w = (const float*)d_in[12];
    const float* blk_w  = (const float*)d_in[13];
    const float* blk_b  = (const float*)d_in[14];
    float* out = (float*)d_out;

    float* ws = (float*)d_ws;
    size_t o = 0;
    float* in_wT  = ws + o; o += (size_t)4 * 256 * 128;
    float* x_wT   = ws + o; o += (size_t)4 * 192 * 128;
    float* out_wT = ws + o; o += (size_t)4 * 128 * 128;
    float* dt_wT  = ws + o; o += (size_t)4 * 128 * 32;
    const size_t NE = (size_t)BN * LSEQ * DM;  // 3,772,416
    float* xn    = ws + o; o += NE;            // reused as dmix after K2
    float* xfq   = ws + o; o += NE;
    float* xsb   = ws + o; o += NE;
    float* szb   = ws + o; o += NE;
    float* delta = ws + o; o += NE;
    float* dbcd  = ws + o; o += (size_t)BN * LSEQ * 192;
    float* dmix  = xn;

    hipLaunchKernelGGL(k_transpose, dim3(512, 4), dim3(256), 0, stream,
                       in_w, x_w, out_w, dt_w, in_wT, x_wT, out_wT, dt_wT);

    for (int e = 0; e < 4; ++e) {
        const float* xcur = (e == 0) ? x_in : (const float*)out;
        const int last = (e == 3) ? 1 : 0;
        hipLaunchKernelGGL(k_freq, dim3(BN), dim3(128), 0, stream,
                           xcur, norm_w, fw_r, fw_i, xn, xfq, e);
        hipLaunchKernelGGL(k_inproj, dim3(BN), dim3(256), 0, stream,
                           xn, in_wT, in_b, xsb, szb, e);
        hipLaunchKernelGGL(k_xproj, dim3(BN), dim3(192), 0, stream,
                           xsb, x_wT, dt_wT, dt_b, dbcd, delta, e);
        hipLaunchKernelGGL(k_graphmix, dim3(96, 10), dim3(128), 0, stream,
                           delta, graph, dmix);
        hipLaunchKernelGGL(k_ssm, dim3(BN), dim3(128), 0, stream,
                           dmix, xsb, szb, xfq, dbcd, A_log, out_wT, out_b,
                           blk_w, blk_b, xcur, out, e, last);
    }
}

// Round 2
// 847.891 us; speedup vs baseline: 1.2854x; 1.2854x over previous
//
#include <hip/hip_runtime.h>
#include <math.h>

#define BN    2456
#define LSEQ  12
#define DM    128
#define NODES 307
#define MROWS 29472   // BN * LSEQ

typedef __bf16 bfx8 __attribute__((ext_vector_type(8)));
typedef float  f32x4 __attribute__((ext_vector_type(4)));

#define MFMA16(a, b, c) __builtin_amdgcn_mfma_f32_16x16x32_bf16(a, b, c, 0, 0, 0)

// ---------------- K0: convert/transpose weights once per call ----------------
// layout: in_w[E,256,128] -> bf16 same; x_w[E,192,128] -> bf16; out_w[E,128,128] -> bf16;
// dt_w[E,128,32] -> fp32 dt_wT[E,32,128]; graph[96,128,128] -> bf16 graphT[96,128(a),128(d)]
__global__ __launch_bounds__(256)
void k_convert(const float* __restrict__ in_w, const float* __restrict__ x_w,
               const float* __restrict__ out_w, const float* __restrict__ dt_w,
               const float* __restrict__ graph,
               __bf16* __restrict__ in_w_bf, __bf16* __restrict__ x_w_bf,
               __bf16* __restrict__ out_w_bf, float* __restrict__ dt_wT,
               __bf16* __restrict__ graphT_bf) {
    int idx = blockIdx.x * 256 + threadIdx.x;
    if (idx < 131072) { in_w_bf[idx] = (__bf16)in_w[idx]; return; }
    idx -= 131072;
    if (idx < 98304) { x_w_bf[idx] = (__bf16)x_w[idx]; return; }
    idx -= 98304;
    if (idx < 65536) { out_w_bf[idx] = (__bf16)out_w[idx]; return; }
    idx -= 65536;
    if (idx < 65536) {
        int e = idx >> 12, r = idx & 4095;
        int d = r >> 5, k = r & 31;
        dt_wT[e * 4096 + k * 128 + d] = dt_w[idx];
        return;
    }
    idx -= 65536;
    if (idx < 1572864) {
        int bl = idx >> 14, r = idx & 16383;
        int d = r >> 7, a = r & 127;
        graphT_bf[(size_t)bl * 16384 + a * 128 + d] = (__bf16)graph[idx];
    }
}

// ---------------- block reductions over 128 threads (2 waves) ----------------
template <int N>
__device__ __forceinline__ void red_sum128(float* v, float* sred, int tid) {
#pragma unroll
    for (int off = 32; off; off >>= 1)
#pragma unroll
        for (int i = 0; i < N; ++i) v[i] += __shfl_xor(v[i], off, 64);
    if ((tid & 63) == 0) {
#pragma unroll
        for (int i = 0; i < N; ++i) sred[(tid >> 6) * N + i] = v[i];
    }
    __syncthreads();
#pragma unroll
    for (int i = 0; i < N; ++i) v[i] = sred[i] + sred[N + i];
    __syncthreads();
}

template <int N>
__device__ __forceinline__ void red_max128(float* v, float* sred, int tid) {
#pragma unroll
    for (int off = 32; off; off >>= 1)
#pragma unroll
        for (int i = 0; i < N; ++i) v[i] = fmaxf(v[i], __shfl_xor(v[i], off, 64));
    if ((tid & 63) == 0) {
#pragma unroll
        for (int i = 0; i < N; ++i) sred[(tid >> 6) * N + i] = v[i];
    }
    __syncthreads();
#pragma unroll
    for (int i = 0; i < N; ++i) v[i] = fmaxf(sred[i], sred[N + i]);
    __syncthreads();
}

// ---------------- K1: rmsnorm + frequency gating -> bf16 xn, bf16 xfreq ----------------
__global__ __launch_bounds__(128)
void k_freq(const float* __restrict__ xcur, const float* __restrict__ norm_w,
            const float* __restrict__ fw_r, const float* __restrict__ fw_i,
            __bf16* __restrict__ xn_bf, __bf16* __restrict__ xfq_bf, int e) {
    __shared__ float s_c[24], s_s[24];
    __shared__ float s_wr[133], s_wi[133];
    __shared__ float sred[24];
    const int row = blockIdx.x, tid = threadIdx.x;

    if (tid < 24) {
        float sv, cv;
        sincosf(6.283185307179586f * (float)tid / 24.0f, &sv, &cv);
        s_c[tid] = cv; s_s[tid] = sv;
    }
    for (int i = tid; i < 133; i += 128) { s_wr[i] = fw_r[e * 133 + i]; s_wi[i] = fw_i[e * 133 + i]; }

    const float* xp = xcur + (size_t)row * (LSEQ * DM) + tid;
    float xv[12], v[12];
#pragma unroll
    for (int l = 0; l < 12; ++l) { xv[l] = xp[l * DM]; v[l] = xv[l] * xv[l]; }
    __syncthreads();
    red_sum128<12>(v, sred, tid);

    const float nw = norm_w[e * DM + tid];
    float xnr[12];
#pragma unroll
    for (int l = 0; l < 12; ++l)
        xnr[l] = xv[l] * rsqrtf(v[l] * (1.0f / 128.0f) + 1e-5f) * nw;

    __bf16* xnp = xn_bf + (size_t)row * (LSEQ * DM) + tid;
#pragma unroll
    for (int l = 0; l < 12; ++l) xnp[l * DM] = (__bf16)xnr[l];

    // DFTs: f (n=12, 7 bins), fp (n=24 padded, 13 bins)
    float fr[7], fi[7], fpr[13], fpi[13];
#pragma unroll
    for (int o2 = 0; o2 < 7; ++o2) { fr[o2] = 0.f; fi[o2] = 0.f; }
#pragma unroll
    for (int k = 0; k < 13; ++k) { fpr[k] = 0.f; fpi[k] = 0.f; }
#pragma unroll
    for (int l = 0; l < 12; ++l) {
#pragma unroll
        for (int o2 = 0; o2 < 7; ++o2) {
            const int t = (2 * o2 * l) % 24;
            fr[o2] += xnr[l] * s_c[t];
            fi[o2] -= xnr[l] * s_s[t];
        }
#pragma unroll
        for (int k = 0; k < 13; ++k) {
            const int t = (k * l) % 24;
            fpr[k] += xnr[l] * s_c[t];
            fpi[k] -= xnr[l] * s_s[t];
        }
    }

    // top-6 of (f.re+U)^2+(f.im+U)^2 descending
    float a7[7];
#pragma unroll
    for (int o2 = 0; o2 < 7; ++o2) {
        float ar = fr[o2] + 1e-6f, ai = fi[o2] + 1e-6f;
        a7[o2] = ar * ar + ai * ai;
    }
#pragma unroll
    for (int pss = 0; pss < 6; ++pss)
#pragma unroll
        for (int j = 0; j < 6; ++j) {
            float hi = fmaxf(a7[j], a7[j + 1]);
            float lo = fminf(a7[j], a7[j + 1]);
            a7[j] = hi; a7[j + 1] = lo;
        }

    float p7[7];
#pragma unroll
    for (int o2 = 0; o2 < 7; ++o2) {
        float pr = 0.f, pi = 0.f;
#pragma unroll
        for (int k = 0; k < 13; ++k) {
            const float wr = s_wr[o2 * 19 + k], wi = s_wi[o2 * 19 + k];
            pr += fpr[k] * wr - fpi[k] * wi;
            pi += fpr[k] * wi + fpi[k] * wr;
        }
#pragma unroll
        for (int k = 0; k < 6; ++k) {
            const float wr = s_wr[o2 * 19 + 13 + k], wi = s_wi[o2 * 19 + 13 + k];
            pr += a7[k] * wr;
            pi += a7[k] * wi;
        }
        p7[o2] = pr * pr + pi * pi;
    }

    float m7[7], ex[7], sm[7];
#pragma unroll
    for (int o2 = 0; o2 < 7; ++o2) m7[o2] = p7[o2];
    red_max128<7>(m7, sred, tid);
#pragma unroll
    for (int o2 = 0; o2 < 7; ++o2) { ex[o2] = expf(p7[o2] - m7[o2]); sm[o2] = ex[o2]; }
    red_sum128<7>(sm, sred, tid);

    float gr[7], gi[7];
#pragma unroll
    for (int o2 = 0; o2 < 7; ++o2) {
        const float wf = ex[o2] / sm[o2];
        gr[o2] = wf * fr[o2];
        gi[o2] = wf * fi[o2];
    }

    __bf16* xfp = xfq_bf + (size_t)row * (LSEQ * DM) + tid;
#pragma unroll
    for (int l = 0; l < 12; ++l) {
        float val = gr[0] + ((l & 1) ? -gr[6] : gr[6]);
#pragma unroll
        for (int o2 = 1; o2 < 6; ++o2) {
            const int t = (2 * o2 * l) % 24;
            val += 2.0f * (gr[o2] * s_c[t] - gi[o2] * s_s[t]);
        }
        xfp[l * DM] = (__bf16)(val * (1.0f / 12.0f));
    }
}

// ---------------- K2: in_proj MFMA GEMM + silu -> xs_bf, sz_bf ----------------
// grid (307, 2) x 192. block rows=96 (3 waves x 2 subtiles), cols = 128 per blockIdx.y
__global__ __launch_bounds__(192)
void gemm_in(const __bf16* __restrict__ Abf, const __bf16* __restrict__ Wbf,
             const float* __restrict__ in_b, __bf16* __restrict__ xs_bf,
             __bf16* __restrict__ sz_bf, int e) {
    const int tid = threadIdx.x;
    const int wave = tid >> 6, lane = tid & 63;
    const int lm = lane & 15, lq = lane >> 4;
    const int m0 = blockIdx.x * 96 + wave * 32;
    const int n0 = blockIdx.y * 128;
    const __bf16* Wp = Wbf + (size_t)e * 256 * 128;

    f32x4 acc[2][8];
#pragma unroll
    for (int ms = 0; ms < 2; ++ms)
#pragma unroll
        for (int nt = 0; nt < 8; ++nt) acc[ms][nt] = (f32x4){0.f, 0.f, 0.f, 0.f};

#pragma unroll
    for (int kc = 0; kc < 4; ++kc) {
        const int kb = kc * 32 + lq * 8;
        bfx8 a0 = *(const bfx8*)(Abf + (size_t)(m0 + lm) * 128 + kb);
        bfx8 a1 = *(const bfx8*)(Abf + (size_t)(m0 + 16 + lm) * 128 + kb);
#pragma unroll
        for (int nt = 0; nt < 8; ++nt) {
            bfx8 b = *(const bfx8*)(Wp + (size_t)(n0 + nt * 16 + lm) * 128 + kb);
            acc[0][nt] = MFMA16(a0, b, acc[0][nt]);
            acc[1][nt] = MFMA16(a1, b, acc[1][nt]);
        }
    }

#pragma unroll
    for (int nt = 0; nt < 8; ++nt) {
        const int col = n0 + nt * 16 + lm;
        const float bias = in_b[e * 256 + col];
#pragma unroll
        for (int ms = 0; ms < 2; ++ms)
#pragma unroll
            for (int r = 0; r < 4; ++r) {
                const int row = m0 + ms * 16 + lq * 4 + r;
                float v = acc[ms][nt][r] + bias;
                v = v / (1.0f + expf(-v));
                if (col < 128) xs_bf[(size_t)row * 128 + col] = (__bf16)v;
                else           sz_bf[(size_t)row * 128 + (col - 128)] = (__bf16)v;
            }
    }
}

// ---------------- K3: x_proj MFMA GEMM (N=192) + fused dt_proj ----------------
// grid (307) x 192. writes B,C,Dp bf16 -> dbcd_bf[M,160]; delta via dt -> delta_bf[M,128]
__global__ __launch_bounds__(192)
void gemm_xp(const __bf16* __restrict__ xs_bf, const __bf16* __restrict__ Wbf,
             const float* __restrict__ dt_wT, const float* __restrict__ dt_b,
             __bf16* __restrict__ dbcd_bf, __bf16* __restrict__ delta_bf, int e) {
    __shared__ float sdel[96 * 32];
    const int tid = threadIdx.x;
    const int wave = tid >> 6, lane = tid & 63;
    const int lm = lane & 15, lq = lane >> 4;
    const int m0g = blockIdx.x * 96;
    const int m0 = m0g + wave * 32;
    const __bf16* Wp = Wbf + (size_t)e * 192 * 128;

    f32x4 acc[2][12];
#pragma unroll
    for (int ms = 0; ms < 2; ++ms)
#pragma unroll
        for (int nt = 0; nt < 12; ++nt) acc[ms][nt] = (f32x4){0.f, 0.f, 0.f, 0.f};

#pragma unroll
    for (int kc = 0; kc < 4; ++kc) {
        const int kb = kc * 32 + lq * 8;
        bfx8 a0 = *(const bfx8*)(xs_bf + (size_t)(m0 + lm) * 128 + kb);
        bfx8 a1 = *(const bfx8*)(xs_bf + (size_t)(m0 + 16 + lm) * 128 + kb);
#pragma unroll
        for (int nt = 0; nt < 12; ++nt) {
            bfx8 b = *(const bfx8*)(Wp + (size_t)(nt * 16 + lm) * 128 + kb);
            acc[0][nt] = MFMA16(a0, b, acc[0][nt]);
            acc[1][nt] = MFMA16(a1, b, acc[1][nt]);
        }
    }

#pragma unroll
    for (int nt = 0; nt < 12; ++nt) {
        const int col = nt * 16 + lm;
#pragma unroll
        for (int ms = 0; ms < 2; ++ms)
#pragma unroll
            for (int r = 0; r < 4; ++r) {
                const int rl = wave * 32 + ms * 16 + lq * 4 + r;
                const float v = acc[ms][nt][r];
                if (col < 32) sdel[rl * 32 + col] = v;
                else dbcd_bf[(size_t)(m0g + rl) * 160 + (col - 32)] = (__bf16)v;
            }
    }
    __syncthreads();

    // dt: delta[r][c] = softplus(dt_b[c] + sum_k sdel[r][k]*dt_wT[k][c])
    for (int i = tid; i < 96 * 128; i += 192) {
        const int rl = i >> 7, c = i & 127;
        float a = dt_b[e * 128 + c];
        const float* DW = dt_wT + e * 4096 + c;
#pragma unroll
        for (int k = 0; k < 32; ++k) a += sdel[rl * 32 + k] * DW[k * 128];
        const float sp = fmaxf(a, 0.f) + log1pf(expf(-fabsf(a)));
        delta_bf[(size_t)(m0g + rl) * 128 + c] = (__bf16)sp;
    }
}

// ---------------- K4: graph mixing, 96 batched MFMA GEMMs -> dmix f32 ----------------
// grid (96, 5) x 256. block = 4 waves x 16 node-rows = 64 rows; N=128
__global__ __launch_bounds__(256)
void gemm_gm(const __bf16* __restrict__ delta_bf, const __bf16* __restrict__ graphT_bf,
             float* __restrict__ dmix) {
    const int bl = blockIdx.x;
    const int b = bl / 12, l = bl - b * 12;
    const int tid = threadIdx.x;
    const int wave = tid >> 6, lane = tid & 63;
    const int lm = lane & 15, lq = lane >> 4;
    const int nbase = blockIdx.y * 64 + wave * 16;
    const __bf16* Bp = graphT_bf + (size_t)bl * 16384;

    f32x4 acc[8];
#pragma unroll
    for (int nt = 0; nt < 8; ++nt) acc[nt] = (f32x4){0.f, 0.f, 0.f, 0.f};

    const int nodeA = min(nbase + lm, NODES - 1);
    const __bf16* Ap = delta_bf + ((size_t)(b * NODES + nodeA) * 12 + l) * 128;

#pragma unroll
    for (int kc = 0; kc < 4; ++kc) {
        const int kb = kc * 32 + lq * 8;
        bfx8 a = *(const bfx8*)(Ap + kb);
#pragma unroll
        for (int nt = 0; nt < 8; ++nt) {
            bfx8 bb = *(const bfx8*)(Bp + (size_t)(nt * 16 + lm) * 128 + kb);
            acc[nt] = MFMA16(a, bb, acc[nt]);
        }
    }

#pragma unroll
    for (int nt = 0; nt < 8; ++nt)
#pragma unroll
        for (int r = 0; r < 4; ++r) {
            const int node = nbase + lq * 4 + r;
            if (node < NODES)
                dmix[((size_t)(b * NODES + node) * 12 + l) * 128 + nt * 16 + lm] = acc[nt][r];
        }
}

// ---------------- K5: SSM scan + gate -> y_bf ----------------
__global__ __launch_bounds__(128)
void k_scan(const float* __restrict__ dmix, const __bf16* __restrict__ xs_bf,
            const __bf16* __restrict__ sz_bf, const __bf16* __restrict__ xfq_bf,
            const __bf16* __restrict__ dbcd_bf, const float* __restrict__ A_log,
            __bf16* __restrict__ y_bf, int e) {
    __shared__ float sB[192], sC[192];
    const int row = blockIdx.x, tid = threadIdx.x;
    const __bf16* bc = dbcd_bf + (size_t)row * 12 * 160;
    for (int i = tid; i < 192; i += 128) {
        const int l = i >> 4, s = i & 15;
        sB[i] = (float)bc[l * 160 + s];
        sC[i] = (float)bc[l * 160 + 16 + s];
    }
    float As[16];
#pragma unroll
    for (int s = 0; s < 16; ++s) As[s] = -expf(A_log[e * 16 + s]);
    __syncthreads();

    const float* dmp = dmix + (size_t)row * 1536 + tid;
    const __bf16* xsp = xs_bf + (size_t)row * 1536 + tid;
    const __bf16* szp = sz_bf + (size_t)row * 1536 + tid;
    const __bf16* xfp = xfq_bf + (size_t)row * 1536 + tid;
    __bf16* yp = y_bf + (size_t)row * 1536 + tid;

    float h[16];
#pragma unroll
    for (int s = 0; s < 16; ++s) h[s] = 0.f;
#pragma unroll
    for (int l = 0; l < 12; ++l) {
        const float dl = dmp[l * 128];
        const float xv = (float)xsp[l * 128];
        const float Dp = (float)bc[l * 160 + 32 + tid];
        float y = 0.f;
#pragma unroll
        for (int s = 0; s < 16; ++s) {
            h[s] = expf(dl * As[s]) * h[s] + dl * sB[l * 16 + s] * xv;
            y += h[s] * sC[l * 16 + s];
        }
        y += Dp * xv;
        const float g = y * (float)szp[l * 128] * (float)xfp[l * 128];
        yp[l * 128] = (__bf16)g;
    }
}

// ---------------- K6: out_proj MFMA GEMM + residual (+final silu) ----------------
// grid (307) x 192
__global__ __launch_bounds__(192)
void gemm_out(const __bf16* __restrict__ y_bf, const __bf16* __restrict__ Wbf,
              const float* __restrict__ out_b, const float* __restrict__ blk_w,
              const float* __restrict__ blk_b, const float* __restrict__ xprev,
              float* __restrict__ xout, int e, int last) {
    const int tid = threadIdx.x;
    const int wave = tid >> 6, lane = tid & 63;
    const int lm = lane & 15, lq = lane >> 4;
    const int m0 = blockIdx.x * 96 + wave * 32;
    const __bf16* Wp = Wbf + (size_t)e * 128 * 128;

    f32x4 acc[2][8];
#pragma unroll
    for (int ms = 0; ms < 2; ++ms)
#pragma unroll
        for (int nt = 0; nt < 8; ++nt) acc[ms][nt] = (f32x4){0.f, 0.f, 0.f, 0.f};

#pragma unroll
    for (int kc = 0; kc < 4; ++kc) {
        const int kb = kc * 32 + lq * 8;
        bfx8 a0 = *(const bfx8*)(y_bf + (size_t)(m0 + lm) * 128 + kb);
        bfx8 a1 = *(const bfx8*)(y_bf + (size_t)(m0 + 16 + lm) * 128 + kb);
#pragma unroll
        for (int nt = 0; nt < 8; ++nt) {
            bfx8 b = *(const bfx8*)(Wp + (size_t)(nt * 16 + lm) * 128 + kb);
            acc[0][nt] = MFMA16(a0, b, acc[0][nt]);
            acc[1][nt] = MFMA16(a1, b, acc[1][nt]);
        }
    }

    const float bw = blk_w[e], bb = blk_b[e];
#pragma unroll
    for (int nt = 0; nt < 8; ++nt) {
        const int col = nt * 16 + lm;
        const float ob = out_b[e * 128 + col];
#pragma unroll
        for (int ms = 0; ms < 2; ++ms)
#pragma unroll
            for (int r = 0; r < 4; ++r) {
                const int row = m0 + ms * 16 + lq * 4 + r;
                float v = bw * (acc[ms][nt][r] + ob) + bb + xprev[(size_t)row * 128 + col];
                if (last) v = v / (1.0f + expf(-v));
                xout[(size_t)row * 128 + col] = v;
            }
    }
}

extern "C" void kernel_launch(void* const* d_in, const int* in_sizes, int n_in,
                              void* d_out, int out_size, void* d_ws, size_t ws_size,
                              hipStream_t stream) {
    (void)in_sizes; (void)n_in; (void)out_size; (void)ws_size;
    const float* x_in   = (const float*)d_in[0];
    const float* graph  = (const float*)d_in[1];
    const float* in_w   = (const float*)d_in[2];
    const float* in_b   = (const float*)d_in[3];
    const float* x_w    = (const float*)d_in[4];
    const float* dt_w   = (const float*)d_in[5];
    const float* dt_b   = (const float*)d_in[6];
    const float* A_log  = (const float*)d_in[7];
    const float* out_w  = (const float*)d_in[8];
    const float* out_b  = (const float*)d_in[9];
    const float* fw_r   = (const float*)d_in[10];
    const float* fw_i   = (const float*)d_in[11];
    const float* norm_w = (const float*)d_in[12];
    const float* blk_w  = (const float*)d_in[13];
    const float* blk_b  = (const float*)d_in[14];
    float* out = (float*)d_out;

    float* ws = (float*)d_ws;
    size_t o = 0;
    __bf16* in_w_bf   = (__bf16*)(ws + o); o += 131072 / 2;
    __bf16* x_w_bf    = (__bf16*)(ws + o); o += 98304 / 2;
    __bf16* out_w_bf  = (__bf16*)(ws + o); o += 65536 / 2;
    float*  dt_wT     = ws + o;            o += 65536;
    __bf16* graphT_bf = (__bf16*)(ws + o); o += 1572864 / 2;
    const size_t NE = (size_t)MROWS * 128;            // 3,772,416 elements
    __bf16* xn_bf    = (__bf16*)(ws + o); o += NE / 2;
    __bf16* xfq_bf   = (__bf16*)(ws + o); o += NE / 2;
    __bf16* xs_bf    = (__bf16*)(ws + o); o += NE / 2;
    __bf16* sz_bf    = (__bf16*)(ws + o); o += NE / 2;
    __bf16* y_bf     = (__bf16*)(ws + o); o += NE / 2;
    __bf16* delta_bf = (__bf16*)(ws + o); o += NE / 2;
    __bf16* dbcd_bf  = (__bf16*)(ws + o); o += (size_t)MROWS * 160 / 2;
    float*  dmix     = ws + o;            o += NE;

    hipLaunchKernelGGL(k_convert, dim3(7552), dim3(256), 0, stream,
                       in_w, x_w, out_w, dt_w, graph,
                       in_w_bf, x_w_bf, out_w_bf, dt_wT, graphT_bf);

    for (int e = 0; e < 4; ++e) {
        const float* xcur = (e == 0) ? x_in : (const float*)out;
        const int last = (e == 3) ? 1 : 0;
        hipLaunchKernelGGL(k_freq, dim3(BN), dim3(128), 0, stream,
                           xcur, norm_w, fw_r, fw_i, xn_bf, xfq_bf, e);
        hipLaunchKernelGGL(gemm_in, dim3(307, 2), dim3(192), 0, stream,
                           xn_bf, in_w_bf, in_b, xs_bf, sz_bf, e);
        hipLaunchKernelGGL(gemm_xp, dim3(307), dim3(192), 0, stream,
                           xs_bf, x_w_bf, dt_wT, dt_b, dbcd_bf, delta_bf, e);
        hipLaunchKernelGGL(gemm_gm, dim3(96, 5), dim3(256), 0, stream,
                           delta_bf, graphT_bf, dmix);
        hipLaunchKernelGGL(k_scan, dim3(BN), dim3(128), 0, stream,
                           dmix, xs_bf, sz_bf, xfq_bf, dbcd_bf, A_log, y_bf, e);
        hipLaunchKernelGGL(gemm_out, dim3(307), dim3(192), 0, stream,
                           y_bf, out_w_bf, out_b, blk_w, blk_b, xcur, out, e, last);
    }
}

// Round 4
// 732.413 us; speedup vs baseline: 1.4881x; 1.1577x over previous
//
#include <hip/hip_runtime.h>
#include <math.h>

#define BN    2456
#define LSEQ  12
#define DM    128
#define NODES 307
#define MROWS 29472   // BN * LSEQ

typedef __bf16 bfx8 __attribute__((ext_vector_type(8)));
typedef float  f32x4 __attribute__((ext_vector_type(4)));

#define MFMA16(a, b, c) __builtin_amdgcn_mfma_f32_16x16x32_bf16(a, b, c, 0, 0, 0)

// ---------------- K0: convert weights to bf16 once per call ----------------
// in_w[E,256,128]->bf16; x_w[E,192,128]->bf16; out_w[E,128,128]->bf16;
// dt_w[E,128,32]->bf16 (no transpose: already B-fragment layout);
// graph[96,128,128]->bf16 graphT[96,128(a),128(d)]
__global__ __launch_bounds__(256)
void k_convert(const float* __restrict__ in_w, const float* __restrict__ x_w,
               const float* __restrict__ out_w, const float* __restrict__ dt_w,
               const float* __restrict__ graph,
               __bf16* __restrict__ in_w_bf, __bf16* __restrict__ x_w_bf,
               __bf16* __restrict__ out_w_bf, __bf16* __restrict__ dtw_bf,
               __bf16* __restrict__ graphT_bf) {
    int idx = blockIdx.x * 256 + threadIdx.x;
    if (idx < 131072) { in_w_bf[idx] = (__bf16)in_w[idx]; return; }
    idx -= 131072;
    if (idx < 98304) { x_w_bf[idx] = (__bf16)x_w[idx]; return; }
    idx -= 98304;
    if (idx < 65536) { out_w_bf[idx] = (__bf16)out_w[idx]; return; }
    idx -= 65536;
    if (idx < 65536) { dtw_bf[idx] = (__bf16)dt_w[idx]; return; }
    idx -= 65536;
    if (idx < 1572864) {
        int bl = idx >> 14, r = idx & 16383;
        int d = r >> 7, a = r & 127;
        graphT_bf[(size_t)bl * 16384 + a * 128 + d] = (__bf16)graph[idx];
    }
}

// ---------------- block reductions over 128 threads (2 waves) ----------------
template <int N>
__device__ __forceinline__ void red_sum128(float* v, float* sred, int tid) {
#pragma unroll
    for (int off = 32; off; off >>= 1)
#pragma unroll
        for (int i = 0; i < N; ++i) v[i] += __shfl_xor(v[i], off, 64);
    if ((tid & 63) == 0) {
#pragma unroll
        for (int i = 0; i < N; ++i) sred[(tid >> 6) * N + i] = v[i];
    }
    __syncthreads();
#pragma unroll
    for (int i = 0; i < N; ++i) v[i] = sred[i] + sred[N + i];
    __syncthreads();
}

template <int N>
__device__ __forceinline__ void red_max128(float* v, float* sred, int tid) {
#pragma unroll
    for (int off = 32; off; off >>= 1)
#pragma unroll
        for (int i = 0; i < N; ++i) v[i] = fmaxf(v[i], __shfl_xor(v[i], off, 64));
    if ((tid & 63) == 0) {
#pragma unroll
        for (int i = 0; i < N; ++i) sred[(tid >> 6) * N + i] = v[i];
    }
    __syncthreads();
#pragma unroll
    for (int i = 0; i < N; ++i) v[i] = fmaxf(sred[i], sred[N + i]);
    __syncthreads();
}

// ---------------- K1: rmsnorm + frequency gating -> bf16 xn, bf16 xfreq ----------------
__global__ __launch_bounds__(128)
void k_freq(const float* __restrict__ xcur, const float* __restrict__ norm_w,
            const float* __restrict__ fw_r, const float* __restrict__ fw_i,
            __bf16* __restrict__ xn_bf, __bf16* __restrict__ xfq_bf, int e) {
    __shared__ float s_c[24], s_s[24];
    __shared__ float s_wr[133], s_wi[133];
    __shared__ float sred[24];
    const int row = blockIdx.x, tid = threadIdx.x;

    if (tid < 24) {
        float sv, cv;
        sincosf(6.283185307179586f * (float)tid / 24.0f, &sv, &cv);
        s_c[tid] = cv; s_s[tid] = sv;
    }
    for (int i = tid; i < 133; i += 128) { s_wr[i] = fw_r[e * 133 + i]; s_wi[i] = fw_i[e * 133 + i]; }

    const float* xp = xcur + (size_t)row * (LSEQ * DM) + tid;
    float xv[12], v[12];
#pragma unroll
    for (int l = 0; l < 12; ++l) { xv[l] = xp[l * DM]; v[l] = xv[l] * xv[l]; }
    __syncthreads();
    red_sum128<12>(v, sred, tid);

    const float nw = norm_w[e * DM + tid];
    float xnr[12];
#pragma unroll
    for (int l = 0; l < 12; ++l)
        xnr[l] = xv[l] * rsqrtf(v[l] * (1.0f / 128.0f) + 1e-5f) * nw;

    __bf16* xnp = xn_bf + (size_t)row * (LSEQ * DM) + tid;
#pragma unroll
    for (int l = 0; l < 12; ++l) xnp[l * DM] = (__bf16)xnr[l];

    float fr[7], fi[7], fpr[13], fpi[13];
#pragma unroll
    for (int o2 = 0; o2 < 7; ++o2) { fr[o2] = 0.f; fi[o2] = 0.f; }
#pragma unroll
    for (int k = 0; k < 13; ++k) { fpr[k] = 0.f; fpi[k] = 0.f; }
#pragma unroll
    for (int l = 0; l < 12; ++l) {
#pragma unroll
        for (int o2 = 0; o2 < 7; ++o2) {
            const int t = (2 * o2 * l) % 24;
            fr[o2] += xnr[l] * s_c[t];
            fi[o2] -= xnr[l] * s_s[t];
        }
#pragma unroll
        for (int k = 0; k < 13; ++k) {
            const int t = (k * l) % 24;
            fpr[k] += xnr[l] * s_c[t];
            fpi[k] -= xnr[l] * s_s[t];
        }
    }

    float a7[7];
#pragma unroll
    for (int o2 = 0; o2 < 7; ++o2) {
        float ar = fr[o2] + 1e-6f, ai = fi[o2] + 1e-6f;
        a7[o2] = ar * ar + ai * ai;
    }
#pragma unroll
    for (int pss = 0; pss < 6; ++pss)
#pragma unroll
        for (int j = 0; j < 6; ++j) {
            float hi = fmaxf(a7[j], a7[j + 1]);
            float lo = fminf(a7[j], a7[j + 1]);
            a7[j] = hi; a7[j + 1] = lo;
        }

    float p7[7];
#pragma unroll
    for (int o2 = 0; o2 < 7; ++o2) {
        float pr = 0.f, pi = 0.f;
#pragma unroll
        for (int k = 0; k < 13; ++k) {
            const float wr = s_wr[o2 * 19 + k], wi = s_wi[o2 * 19 + k];
            pr += fpr[k] * wr - fpi[k] * wi;
            pi += fpr[k] * wi + fpi[k] * wr;
        }
#pragma unroll
        for (int k = 0; k < 6; ++k) {
            const float wr = s_wr[o2 * 19 + 13 + k], wi = s_wi[o2 * 19 + 13 + k];
            pr += a7[k] * wr;
            pi += a7[k] * wi;
        }
        p7[o2] = pr * pr + pi * pi;
    }

    float m7[7], ex[7], sm[7];
#pragma unroll
    for (int o2 = 0; o2 < 7; ++o2) m7[o2] = p7[o2];
    red_max128<7>(m7, sred, tid);
#pragma unroll
    for (int o2 = 0; o2 < 7; ++o2) { ex[o2] = expf(p7[o2] - m7[o2]); sm[o2] = ex[o2]; }
    red_sum128<7>(sm, sred, tid);

    float gr[7], gi[7];
#pragma unroll
    for (int o2 = 0; o2 < 7; ++o2) {
        const float wf = ex[o2] / sm[o2];
        gr[o2] = wf * fr[o2];
        gi[o2] = wf * fi[o2];
    }

    __bf16* xfp = xfq_bf + (size_t)row * (LSEQ * DM) + tid;
#pragma unroll
    for (int l = 0; l < 12; ++l) {
        float val = gr[0] + ((l & 1) ? -gr[6] : gr[6]);
#pragma unroll
        for (int o2 = 1; o2 < 6; ++o2) {
            const int t = (2 * o2 * l) % 24;
            val += 2.0f * (gr[o2] * s_c[t] - gi[o2] * s_s[t]);
        }
        xfp[l * DM] = (__bf16)(val * (1.0f / 12.0f));
    }
}

// ---------------- K2: in_proj MFMA GEMM + silu ----------------
// grid (614, 2) x 192. block = 48 rows (3 waves x 1 m-tile), 128 cols per blockIdx.y
__global__ __launch_bounds__(192)
void gemm_in(const __bf16* __restrict__ Abf, const __bf16* __restrict__ Wbf,
             const float* __restrict__ in_b, __bf16* __restrict__ xs_bf,
             __bf16* __restrict__ sz_bf, int e) {
    const int tid = threadIdx.x;
    const int wave = tid >> 6, lane = tid & 63;
    const int lm = lane & 15, lq = lane >> 4;
    const int m0 = blockIdx.x * 48 + wave * 16;
    const int n0 = blockIdx.y * 128;
    const __bf16* Wp = Wbf + (size_t)e * 256 * 128;

    f32x4 acc[8];
#pragma unroll
    for (int nt = 0; nt < 8; ++nt) acc[nt] = (f32x4){0.f, 0.f, 0.f, 0.f};

#pragma unroll
    for (int kc = 0; kc < 4; ++kc) {
        const int kb = kc * 32 + lq * 8;
        bfx8 a = *(const bfx8*)(Abf + (size_t)(m0 + lm) * 128 + kb);
#pragma unroll
        for (int nt = 0; nt < 8; ++nt) {
            bfx8 b = *(const bfx8*)(Wp + (size_t)(n0 + nt * 16 + lm) * 128 + kb);
            acc[nt] = MFMA16(a, b, acc[nt]);
        }
    }

#pragma unroll
    for (int nt = 0; nt < 8; ++nt) {
        const int col = n0 + nt * 16 + lm;
        const float bias = in_b[e * 256 + col];
#pragma unroll
        for (int r = 0; r < 4; ++r) {
            const int row = m0 + lq * 4 + r;
            float v = acc[nt][r] + bias;
            v = v / (1.0f + expf(-v));
            if (col < 128) xs_bf[(size_t)row * 128 + col] = (__bf16)v;
            else           sz_bf[(size_t)row * 128 + (col - 128)] = (__bf16)v;
        }
    }
}

// ---------------- K3: x_proj MFMA GEMM (N=192) + MFMA dt_proj ----------------
// grid (614) x 192. 48 rows/block. B,C,Dp -> dbcd_bf[M,160]; delta -> delta_bf[M,128]
__global__ __launch_bounds__(192)
void gemm_xp(const __bf16* __restrict__ xs_bf, const __bf16* __restrict__ Wbf,
             const __bf16* __restrict__ dtw_bf, const float* __restrict__ dt_b,
             __bf16* __restrict__ dbcd_bf, __bf16* __restrict__ delta_bf, int e) {
    __shared__ __bf16 sdel[48 * 40];   // 48 rows x 32 cols, padded to 40 (bank-friendly)
    const int tid = threadIdx.x;
    const int wave = tid >> 6, lane = tid & 63;
    const int lm = lane & 15, lq = lane >> 4;
    const int m0g = blockIdx.x * 48;
    const int m0 = m0g + wave * 16;
    const __bf16* Wp = Wbf + (size_t)e * 192 * 128;

    f32x4 acc[12];
#pragma unroll
    for (int nt = 0; nt < 12; ++nt) acc[nt] = (f32x4){0.f, 0.f, 0.f, 0.f};

#pragma unroll
    for (int kc = 0; kc < 4; ++kc) {
        const int kb = kc * 32 + lq * 8;
        bfx8 a = *(const bfx8*)(xs_bf + (size_t)(m0 + lm) * 128 + kb);
#pragma unroll
        for (int nt = 0; nt < 12; ++nt) {
            bfx8 b = *(const bfx8*)(Wp + (size_t)(nt * 16 + lm) * 128 + kb);
            acc[nt] = MFMA16(a, b, acc[nt]);
        }
    }

#pragma unroll
    for (int nt = 0; nt < 12; ++nt) {
        const int col = nt * 16 + lm;
#pragma unroll
        for (int r = 0; r < 4; ++r) {
            const int rl = wave * 16 + lq * 4 + r;
            const float v = acc[nt][r];
            if (col < 32) sdel[rl * 40 + col] = (__bf16)v;
            else dbcd_bf[(size_t)(m0g + rl) * 160 + (col - 32)] = (__bf16)v;
        }
    }
    __syncthreads();

    // dt projection via MFMA: [48 x 32] @ dt_w^T -> [48 x 128], K=32 in one step
    const __bf16* DWp = dtw_bf + (size_t)e * 128 * 32;
    bfx8 a = *(const bfx8*)(sdel + (wave * 16 + lm) * 40 + lq * 8);
    const f32x4 zero4 = {0.f, 0.f, 0.f, 0.f};
    f32x4 dacc[8];
#pragma unroll
    for (int nt = 0; nt < 8; ++nt) {
        bfx8 b = *(const bfx8*)(DWp + (size_t)(nt * 16 + lm) * 32 + lq * 8);
        dacc[nt] = MFMA16(a, b, zero4);
    }
#pragma unroll
    for (int nt = 0; nt < 8; ++nt) {
        const int col = nt * 16 + lm;
        const float bias = dt_b[e * 128 + col];
#pragma unroll
        for (int r = 0; r < 4; ++r) {
            const int m = m0g + wave * 16 + lq * 4 + r;
            const float x = dacc[nt][r] + bias;
            const float sp = fmaxf(x, 0.f) + log1pf(expf(-fabsf(x)));
            delta_bf[(size_t)m * 128 + col] = (__bf16)sp;
        }
    }
}

// ---------------- K4: graph mixing, 96 batched MFMA GEMMs -> dmix f32 ----------------
// grid (96, 5, 2) x 256. wave = 16 node-rows x 64 cols
__global__ __launch_bounds__(256)
void gemm_gm(const __bf16* __restrict__ delta_bf, const __bf16* __restrict__ graphT_bf,
             float* __restrict__ dmix) {
    const int bl = blockIdx.x;
    const int b = bl / 12, l = bl - b * 12;
    const int tid = threadIdx.x;
    const int wave = tid >> 6, lane = tid & 63;
    const int lm = lane & 15, lq = lane >> 4;
    const int nbase = blockIdx.y * 64 + wave * 16;
    const int n0c = blockIdx.z * 64;
    const __bf16* Bp = graphT_bf + (size_t)bl * 16384;

    f32x4 acc[4];
#pragma unroll
    for (int nt = 0; nt < 4; ++nt) acc[nt] = (f32x4){0.f, 0.f, 0.f, 0.f};

    const int nodeA = min(nbase + lm, NODES - 1);
    const __bf16* Ap = delta_bf + ((size_t)(b * NODES + nodeA) * 12 + l) * 128;

#pragma unroll
    for (int kc = 0; kc < 4; ++kc) {
        const int kb = kc * 32 + lq * 8;
        bfx8 a = *(const bfx8*)(Ap + kb);
#pragma unroll
        for (int nt = 0; nt < 4; ++nt) {
            bfx8 bb = *(const bfx8*)(Bp + (size_t)(n0c + nt * 16 + lm) * 128 + kb);
            acc[nt] = MFMA16(a, bb, acc[nt]);
        }
    }

#pragma unroll
    for (int nt = 0; nt < 4; ++nt)
#pragma unroll
        for (int r = 0; r < 4; ++r) {
            const int node = nbase + lq * 4 + r;
            if (node < NODES)
                dmix[((size_t)(b * NODES + node) * 12 + l) * 128 + n0c + nt * 16 + lm] = acc[nt][r];
        }
}

// ---------------- K5: SSM scan + gate -> y_bf ----------------
__global__ __launch_bounds__(128)
void k_scan(const float* __restrict__ dmix, const __bf16* __restrict__ xs_bf,
            const __bf16* __restrict__ sz_bf, const __bf16* __restrict__ xfq_bf,
            const __bf16* __restrict__ dbcd_bf, const float* __restrict__ A_log,
            __bf16* __restrict__ y_bf, int e) {
    __shared__ float sB[192], sC[192];
    const int row = blockIdx.x, tid = threadIdx.x;
    const __bf16* bc = dbcd_bf + (size_t)row * 12 * 160;
    for (int i = tid; i < 192; i += 128) {
        const int l = i >> 4, s = i & 15;
        sB[i] = (float)bc[l * 160 + s];
        sC[i] = (float)bc[l * 160 + 16 + s];
    }
    float As[16];
#pragma unroll
    for (int s = 0; s < 16; ++s) As[s] = -expf(A_log[e * 16 + s]);
    __syncthreads();

    const float* dmp = dmix + (size_t)row * 1536 + tid;
    const __bf16* xsp = xs_bf + (size_t)row * 1536 + tid;
    const __bf16* szp = sz_bf + (size_t)row * 1536 + tid;
    const __bf16* xfp = xfq_bf + (size_t)row * 1536 + tid;
    __bf16* yp = y_bf + (size_t)row * 1536 + tid;

    float h[16];
#pragma unroll
    for (int s = 0; s < 16; ++s) h[s] = 0.f;
#pragma unroll
    for (int l = 0; l < 12; ++l) {
        const float dl = dmp[l * 128];
        const float xv = (float)xsp[l * 128];
        const float Dp = (float)bc[l * 160 + 32 + tid];
        float y = 0.f;
#pragma unroll
        for (int s = 0; s < 16; ++s) {
            h[s] = expf(dl * As[s]) * h[s] + dl * sB[l * 16 + s] * xv;
            y += h[s] * sC[l * 16 + s];
        }
        y += Dp * xv;
        const float g = y * (float)szp[l * 128] * (float)xfp[l * 128];
        yp[l * 128] = (__bf16)g;
    }
}

// ---------------- K6: out_proj MFMA GEMM + residual (+final silu) ----------------
// grid (614, 2) x 192. wave = 16 rows x 64 cols
__global__ __launch_bounds__(192)
void gemm_out(const __bf16* __restrict__ y_bf, const __bf16* __restrict__ Wbf,
              const float* __restrict__ out_b, const float* __restrict__ blk_w,
              const float* __restrict__ blk_b, const float* __restrict__ xprev,
              float* __restrict__ xout, int e, int last) {
    const int tid = threadIdx.x;
    const int wave = tid >> 6, lane = tid & 63;
    const int lm = lane & 15, lq = lane >> 4;
    const int m0 = blockIdx.x * 48 + wave * 16;
    const int n0 = blockIdx.y * 64;
    const __bf16* Wp = Wbf + (size_t)e * 128 * 128;

    f32x4 acc[4];
#pragma unroll
    for (int nt = 0; nt < 4; ++nt) acc[nt] = (f32x4){0.f, 0.f, 0.f, 0.f};

#pragma unroll
    for (int kc = 0; kc < 4; ++kc) {
        const int kb = kc * 32 + lq * 8;
        bfx8 a = *(const bfx8*)(y_bf + (size_t)(m0 + lm) * 128 + kb);
#pragma unroll
        for (int nt = 0; nt < 4; ++nt) {
            bfx8 b = *(const bfx8*)(Wp + (size_t)(n0 + nt * 16 + lm) * 128 + kb);
            acc[nt] = MFMA16(a, b, acc[nt]);
        }
    }

    const float bw = blk_w[e], bb = blk_b[e];
#pragma unroll
    for (int nt = 0; nt < 4; ++nt) {
        const int col = n0 + nt * 16 + lm;
        const float ob = out_b[e * 128 + col];
#pragma unroll
        for (int r = 0; r < 4; ++r) {
            const int row = m0 + lq * 4 + r;
            float v = bw * (acc[nt][r] + ob) + bb + xprev[(size_t)row * 128 + col];
            if (last) v = v / (1.0f + expf(-v));
            xout[(size_t)row * 128 + col] = v;
        }
    }
}

extern "C" void kernel_launch(void* const* d_in, const int* in_sizes, int n_in,
                              void* d_out, int out_size, void* d_ws, size_t ws_size,
                              hipStream_t stream) {
    (void)in_sizes; (void)n_in; (void)out_size; (void)ws_size;
    const float* x_in   = (const float*)d_in[0];
    const float* graph  = (const float*)d_in[1];
    const float* in_w   = (const float*)d_in[2];
    const float* in_b   = (const float*)d_in[3];
    const float* x_w    = (const float*)d_in[4];
    const float* dt_w   = (const float*)d_in[5];
    const float* dt_b   = (const float*)d_in[6];
    const float* A_log  = (const float*)d_in[7];
    const float* out_w  = (const float*)d_in[8];
    const float* out_b  = (const float*)d_in[9];
    const float* fw_r   = (const float*)d_in[10];
    const float* fw_i   = (const float*)d_in[11];
    const float* norm_w = (const float*)d_in[12];
    const float* blk_w  = (const float*)d_in[13];
    const float* blk_b  = (const float*)d_in[14];
    float* out = (float*)d_out;

    float* ws = (float*)d_ws;
    size_t o = 0;
    __bf16* in_w_bf   = (__bf16*)(ws + o); o += 131072 / 2;
    __bf16* x_w_bf    = (__bf16*)(ws + o); o += 98304 / 2;
    __bf16* out_w_bf  = (__bf16*)(ws + o); o += 65536 / 2;
    __bf16* dtw_bf    = (__bf16*)(ws + o); o += 65536 / 2;
    __bf16* graphT_bf = (__bf16*)(ws + o); o += 1572864 / 2;
    const size_t NE = (size_t)MROWS * 128;            // 3,772,416 elements
    __bf16* xn_bf    = (__bf16*)(ws + o); o += NE / 2;
    __bf16* xfq_bf   = (__bf16*)(ws + o); o += NE / 2;
    __bf16* xs_bf    = (__bf16*)(ws + o); o += NE / 2;
    __bf16* sz_bf    = (__bf16*)(ws + o); o += NE / 2;
    __bf16* y_bf     = (__bf16*)(ws + o); o += NE / 2;
    __bf16* delta_bf = (__bf16*)(ws + o); o += NE / 2;
    __bf16* dbcd_bf  = (__bf16*)(ws + o); o += (size_t)MROWS * 160 / 2;
    float*  dmix     = ws + o;            o += NE;

    hipLaunchKernelGGL(k_convert, dim3(7552), dim3(256), 0, stream,
                       in_w, x_w, out_w, dt_w, graph,
                       in_w_bf, x_w_bf, out_w_bf, dtw_bf, graphT_bf);

    for (int e = 0; e < 4; ++e) {
        const float* xcur = (e == 0) ? x_in : (const float*)out;
        const int last = (e == 3) ? 1 : 0;
        hipLaunchKernelGGL(k_freq, dim3(BN), dim3(128), 0, stream,
                           xcur, norm_w, fw_r, fw_i, xn_bf, xfq_bf, e);
        hipLaunchKernelGGL(gemm_in, dim3(614, 2), dim3(192), 0, stream,
                           xn_bf, in_w_bf, in_b, xs_bf, sz_bf, e);
        hipLaunchKernelGGL(gemm_xp, dim3(614), dim3(192), 0, stream,
                           xs_bf, x_w_bf, dtw_bf, dt_b, dbcd_bf, delta_bf, e);
        hipLaunchKernelGGL(gemm_gm, dim3(96, 5, 2), dim3(256), 0, stream,
                           delta_bf, graphT_bf, dmix);
        hipLaunchKernelGGL(k_scan, dim3(BN), dim3(128), 0, stream,
                           dmix, xs_bf, sz_bf, xfq_bf, dbcd_bf, A_log, y_bf, e);
        hipLaunchKernelGGL(gemm_out, dim3(614, 2), dim3(192), 0, stream,
                           y_bf, out_w_bf, out_b, blk_w, blk_b, xcur, out, e, last);
    }
}

// Round 5
// 520.129 us; speedup vs baseline: 2.0954x; 1.4081x over previous
//
#include <hip/hip_runtime.h>
#include <math.h>

#define BN    2456
#define LSEQ  12
#define DM    128
#define NODES 307
#define MROWS 29472   // BN * LSEQ

typedef __bf16 bfx8 __attribute__((ext_vector_type(8)));
typedef float  f32x4 __attribute__((ext_vector_type(4)));

#define MFMA16(a, b, c) __builtin_amdgcn_mfma_f32_16x16x32_bf16(a, b, c, 0, 0, 0)

__device__ __forceinline__ float fsilu(float v)     { return v / (1.0f + __expf(-v)); }
__device__ __forceinline__ float fsoftplus(float x) { return fmaxf(x, 0.f) + __logf(1.0f + __expf(-fabsf(x))); }

// ---------------- K0: convert weights to bf16 once per call ----------------
__global__ __launch_bounds__(256)
void k_convert(const float* __restrict__ in_w, const float* __restrict__ x_w,
               const float* __restrict__ out_w, const float* __restrict__ dt_w,
               const float* __restrict__ graph,
               __bf16* __restrict__ in_w_bf, __bf16* __restrict__ x_w_bf,
               __bf16* __restrict__ out_w_bf, __bf16* __restrict__ dtw_bf,
               __bf16* __restrict__ graphT_bf) {
    int idx = blockIdx.x * 256 + threadIdx.x;
    if (idx < 131072) { in_w_bf[idx] = (__bf16)in_w[idx]; return; }
    idx -= 131072;
    if (idx < 98304) { x_w_bf[idx] = (__bf16)x_w[idx]; return; }
    idx -= 98304;
    if (idx < 65536) { out_w_bf[idx] = (__bf16)out_w[idx]; return; }
    idx -= 65536;
    if (idx < 65536) { dtw_bf[idx] = (__bf16)dt_w[idx]; return; }
    idx -= 65536;
    if (idx < 1572864) {
        int bl = idx >> 14, r = idx & 16383;
        int d = r >> 7, a = r & 127;
        graphT_bf[(size_t)bl * 16384 + a * 128 + d] = (__bf16)graph[idx];
    }
}

// ---------------- block reductions over 128 threads (2 waves) ----------------
template <int N>
__device__ __forceinline__ void red_sum128(float* v, float* sred, int tid) {
#pragma unroll
    for (int off = 32; off; off >>= 1)
#pragma unroll
        for (int i = 0; i < N; ++i) v[i] += __shfl_xor(v[i], off, 64);
    if ((tid & 63) == 0) {
#pragma unroll
        for (int i = 0; i < N; ++i) sred[(tid >> 6) * N + i] = v[i];
    }
    __syncthreads();
#pragma unroll
    for (int i = 0; i < N; ++i) v[i] = sred[i] + sred[N + i];
    __syncthreads();
}

template <int N>
__device__ __forceinline__ void red_max128(float* v, float* sred, int tid) {
#pragma unroll
    for (int off = 32; off; off >>= 1)
#pragma unroll
        for (int i = 0; i < N; ++i) v[i] = fmaxf(v[i], __shfl_xor(v[i], off, 64));
    if ((tid & 63) == 0) {
#pragma unroll
        for (int i = 0; i < N; ++i) sred[(tid >> 6) * N + i] = v[i];
    }
    __syncthreads();
#pragma unroll
    for (int i = 0; i < N; ++i) v[i] = fmaxf(sred[i], sred[N + i]);
    __syncthreads();
}

// ---------------- K1: rmsnorm + frequency gating -> bf16 xn, bf16 xfreq ----------------
__global__ __launch_bounds__(128)
void k_freq(const float* __restrict__ xcur, const float* __restrict__ norm_w,
            const float* __restrict__ fw_r, const float* __restrict__ fw_i,
            __bf16* __restrict__ xn_bf, __bf16* __restrict__ xfq_bf, int e) {
    __shared__ float s_c[24], s_s[24];
    __shared__ float s_wr[133], s_wi[133];
    __shared__ float sred[24];
    const int row = blockIdx.x, tid = threadIdx.x;

    if (tid < 24) {
        float sv, cv;
        __sincosf(6.283185307179586f * (float)tid / 24.0f, &sv, &cv);
        s_c[tid] = cv; s_s[tid] = sv;
    }
    for (int i = tid; i < 133; i += 128) { s_wr[i] = fw_r[e * 133 + i]; s_wi[i] = fw_i[e * 133 + i]; }

    const float* xp = xcur + (size_t)row * (LSEQ * DM) + tid;
    float xv[12], v[12];
#pragma unroll
    for (int l = 0; l < 12; ++l) { xv[l] = xp[l * DM]; v[l] = xv[l] * xv[l]; }
    __syncthreads();
    red_sum128<12>(v, sred, tid);

    const float nw = norm_w[e * DM + tid];
    float xnr[12];
#pragma unroll
    for (int l = 0; l < 12; ++l)
        xnr[l] = xv[l] * rsqrtf(v[l] * (1.0f / 128.0f) + 1e-5f) * nw;

    __bf16* xnp = xn_bf + (size_t)row * (LSEQ * DM) + tid;
#pragma unroll
    for (int l = 0; l < 12; ++l) xnp[l * DM] = (__bf16)xnr[l];

    float fr[7], fi[7], fpr[13], fpi[13];
#pragma unroll
    for (int o2 = 0; o2 < 7; ++o2) { fr[o2] = 0.f; fi[o2] = 0.f; }
#pragma unroll
    for (int k = 0; k < 13; ++k) { fpr[k] = 0.f; fpi[k] = 0.f; }
#pragma unroll
    for (int l = 0; l < 12; ++l) {
#pragma unroll
        for (int o2 = 0; o2 < 7; ++o2) {
            const int t = (2 * o2 * l) % 24;
            fr[o2] += xnr[l] * s_c[t];
            fi[o2] -= xnr[l] * s_s[t];
        }
#pragma unroll
        for (int k = 0; k < 13; ++k) {
            const int t = (k * l) % 24;
            fpr[k] += xnr[l] * s_c[t];
            fpi[k] -= xnr[l] * s_s[t];
        }
    }

    float a7[7];
#pragma unroll
    for (int o2 = 0; o2 < 7; ++o2) {
        float ar = fr[o2] + 1e-6f, ai = fi[o2] + 1e-6f;
        a7[o2] = ar * ar + ai * ai;
    }
#pragma unroll
    for (int pss = 0; pss < 6; ++pss)
#pragma unroll
        for (int j = 0; j < 6; ++j) {
            float hi = fmaxf(a7[j], a7[j + 1]);
            float lo = fminf(a7[j], a7[j + 1]);
            a7[j] = hi; a7[j + 1] = lo;
        }

    float p7[7];
#pragma unroll
    for (int o2 = 0; o2 < 7; ++o2) {
        float pr = 0.f, pi = 0.f;
#pragma unroll
        for (int k = 0; k < 13; ++k) {
            const float wr = s_wr[o2 * 19 + k], wi = s_wi[o2 * 19 + k];
            pr += fpr[k] * wr - fpi[k] * wi;
            pi += fpr[k] * wi + fpi[k] * wr;
        }
#pragma unroll
        for (int k = 0; k < 6; ++k) {
            const float wr = s_wr[o2 * 19 + 13 + k], wi = s_wi[o2 * 19 + 13 + k];
            pr += a7[k] * wr;
            pi += a7[k] * wi;
        }
        p7[o2] = pr * pr + pi * pi;
    }

    float m7[7], ex[7], sm[7];
#pragma unroll
    for (int o2 = 0; o2 < 7; ++o2) m7[o2] = p7[o2];
    red_max128<7>(m7, sred, tid);
#pragma unroll
    for (int o2 = 0; o2 < 7; ++o2) { ex[o2] = __expf(p7[o2] - m7[o2]); sm[o2] = ex[o2]; }
    red_sum128<7>(sm, sred, tid);

    float gr[7], gi[7];
#pragma unroll
    for (int o2 = 0; o2 < 7; ++o2) {
        const float wf = ex[o2] / sm[o2];
        gr[o2] = wf * fr[o2];
        gi[o2] = wf * fi[o2];
    }

    __bf16* xfp = xfq_bf + (size_t)row * (LSEQ * DM) + tid;
#pragma unroll
    for (int l = 0; l < 12; ++l) {
        float val = gr[0] + ((l & 1) ? -gr[6] : gr[6]);
#pragma unroll
        for (int o2 = 1; o2 < 6; ++o2) {
            const int t = (2 * o2 * l) % 24;
            val += 2.0f * (gr[o2] * s_c[t] - gi[o2] * s_s[t]);
        }
        xfp[l * DM] = (__bf16)(val * (1.0f / 12.0f));
    }
}

// ---------------- K2: fused in_proj + silu + x_proj + dt_proj ----------------
// grid (614) x 384 (6 waves). 48 rows/block. mw = wave%3 (m-tile), nw = wave/3 (n-half)
__global__ __launch_bounds__(384)
void gemm_inxp(const __bf16* __restrict__ xn_bf, const __bf16* __restrict__ in_w_bf,
               const float* __restrict__ in_b, const __bf16* __restrict__ x_w_bf,
               const __bf16* __restrict__ dtw_bf, const float* __restrict__ dt_b,
               __bf16* __restrict__ xs_bf, __bf16* __restrict__ sz_bf,
               __bf16* __restrict__ dbcd_bf, __bf16* __restrict__ delta_bf, int e) {
    __shared__ __bf16 sxs[48 * 136];   // stride 136 -> 2-way bank aliasing (free)
    __shared__ __bf16 sdel[48 * 40];
    const int tid = threadIdx.x;
    const int wave = tid >> 6, lane = tid & 63;
    const int lm = lane & 15, lq = lane >> 4;
    const int mw = wave % 3, nw = wave / 3;
    const int m0g = blockIdx.x * 48;
    const int m0 = m0g + mw * 16;

    // ---- phase 1: in_proj (N=256 split in halves across nw) ----
    const __bf16* Wi = in_w_bf + (size_t)e * 256 * 128;
    bfx8 af[4];
#pragma unroll
    for (int kc = 0; kc < 4; ++kc)
        af[kc] = *(const bfx8*)(xn_bf + (size_t)(m0 + lm) * 128 + kc * 32 + lq * 8);

    f32x4 acc[8];
#pragma unroll
    for (int nt = 0; nt < 8; ++nt) acc[nt] = (f32x4){0.f, 0.f, 0.f, 0.f};
#pragma unroll
    for (int kc = 0; kc < 4; ++kc) {
        const int kb = kc * 32 + lq * 8;
#pragma unroll
        for (int nt = 0; nt < 8; ++nt) {
            bfx8 b = *(const bfx8*)(Wi + (size_t)(nw * 128 + nt * 16 + lm) * 128 + kb);
            acc[nt] = MFMA16(af[kc], b, acc[nt]);
        }
    }
#pragma unroll
    for (int nt = 0; nt < 8; ++nt) {
        const int col = nw * 128 + nt * 16 + lm;
        const float bias = in_b[e * 256 + col];
#pragma unroll
        for (int r = 0; r < 4; ++r) {
            const int rl = mw * 16 + lq * 4 + r;
            const int rowg = m0g + rl;
            const float v = fsilu(acc[nt][r] + bias);
            if (col < 128) {
                sxs[rl * 136 + col] = (__bf16)v;
                xs_bf[(size_t)rowg * 128 + col] = (__bf16)v;
            } else {
                sz_bf[(size_t)rowg * 128 + (col - 128)] = (__bf16)v;
            }
        }
    }
    __syncthreads();

    // ---- phase 2: x_proj (N=192, 12 n-tiles split 6/6 across nw), A from LDS ----
    const __bf16* Wx = x_w_bf + (size_t)e * 192 * 128;
    bfx8 ax[4];
#pragma unroll
    for (int kc = 0; kc < 4; ++kc)
        ax[kc] = *(const bfx8*)(sxs + (mw * 16 + lm) * 136 + kc * 32 + lq * 8);

    f32x4 xacc[6];
#pragma unroll
    for (int nt = 0; nt < 6; ++nt) xacc[nt] = (f32x4){0.f, 0.f, 0.f, 0.f};
#pragma unroll
    for (int kc = 0; kc < 4; ++kc) {
        const int kb = kc * 32 + lq * 8;
#pragma unroll
        for (int ntl = 0; ntl < 6; ++ntl) {
            const int nt = nw * 6 + ntl;
            bfx8 b = *(const bfx8*)(Wx + (size_t)(nt * 16 + lm) * 128 + kb);
            xacc[ntl] = MFMA16(ax[kc], b, xacc[ntl]);
        }
    }
#pragma unroll
    for (int ntl = 0; ntl < 6; ++ntl) {
        const int col = (nw * 6 + ntl) * 16 + lm;
#pragma unroll
        for (int r = 0; r < 4; ++r) {
            const int rl = mw * 16 + lq * 4 + r;
            const float v = xacc[ntl][r];
            if (col < 32) sdel[rl * 40 + col] = (__bf16)v;
            else dbcd_bf[(size_t)(m0g + rl) * 160 + (col - 32)] = (__bf16)v;
        }
    }
    __syncthreads();

    // ---- phase 3: dt projection (K=32, one MFMA step), 8 n-tiles split 4/4 ----
    const __bf16* DW = dtw_bf + (size_t)e * 128 * 32;
    bfx8 ad = *(const bfx8*)(sdel + (mw * 16 + lm) * 40 + lq * 8);
    const f32x4 z4 = {0.f, 0.f, 0.f, 0.f};
    f32x4 dacc[4];
#pragma unroll
    for (int ntl = 0; ntl < 4; ++ntl) {
        const int nt = nw * 4 + ntl;
        bfx8 b = *(const bfx8*)(DW + (size_t)(nt * 16 + lm) * 32 + lq * 8);
        dacc[ntl] = MFMA16(ad, b, z4);
    }
#pragma unroll
    for (int ntl = 0; ntl < 4; ++ntl) {
        const int col = (nw * 4 + ntl) * 16 + lm;
        const float bias = dt_b[e * 128 + col];
#pragma unroll
        for (int r = 0; r < 4; ++r) {
            const int m = m0g + mw * 16 + lq * 4 + r;
            delta_bf[(size_t)m * 128 + col] = (__bf16)fsoftplus(dacc[ntl][r] + bias);
        }
    }
}

// ---------------- K3: graph mixing, 96 batched MFMA GEMMs -> dmix f32 ----------------
// grid (96, 5, 2) x 256. wave = 16 node-rows x 64 cols
__global__ __launch_bounds__(256)
void gemm_gm(const __bf16* __restrict__ delta_bf, const __bf16* __restrict__ graphT_bf,
             float* __restrict__ dmix) {
    const int bl = blockIdx.x;
    const int b = bl / 12, l = bl - b * 12;
    const int tid = threadIdx.x;
    const int wave = tid >> 6, lane = tid & 63;
    const int lm = lane & 15, lq = lane >> 4;
    const int nbase = blockIdx.y * 64 + wave * 16;
    const int n0c = blockIdx.z * 64;
    const __bf16* Bp = graphT_bf + (size_t)bl * 16384;

    f32x4 acc[4];
#pragma unroll
    for (int nt = 0; nt < 4; ++nt) acc[nt] = (f32x4){0.f, 0.f, 0.f, 0.f};

    const int nodeA = min(nbase + lm, NODES - 1);
    const __bf16* Ap = delta_bf + ((size_t)(b * NODES + nodeA) * 12 + l) * 128;

#pragma unroll
    for (int kc = 0; kc < 4; ++kc) {
        const int kb = kc * 32 + lq * 8;
        bfx8 a = *(const bfx8*)(Ap + kb);
#pragma unroll
        for (int nt = 0; nt < 4; ++nt) {
            bfx8 bb = *(const bfx8*)(Bp + (size_t)(n0c + nt * 16 + lm) * 128 + kb);
            acc[nt] = MFMA16(a, bb, acc[nt]);
        }
    }

#pragma unroll
    for (int nt = 0; nt < 4; ++nt)
#pragma unroll
        for (int r = 0; r < 4; ++r) {
            const int node = nbase + lq * 4 + r;
            if (node < NODES)
                dmix[((size_t)(b * NODES + node) * 12 + l) * 128 + n0c + nt * 16 + lm] = acc[nt][r];
        }
}

// ---------------- K4: SSM scan + gate + out_proj + residual (+final silu) ----------------
// grid (2456) x 128. scan: thread = d; out_proj: 2 waves x 4 n-tiles
__global__ __launch_bounds__(128)
void k_scanout(const float* __restrict__ dmix, const __bf16* __restrict__ xs_bf,
               const __bf16* __restrict__ sz_bf, const __bf16* __restrict__ xfq_bf,
               const __bf16* __restrict__ dbcd_bf, const float* __restrict__ A_log,
               const __bf16* __restrict__ out_w_bf, const float* __restrict__ out_b,
               const float* __restrict__ blk_w, const float* __restrict__ blk_b,
               const float* __restrict__ xprev, float* __restrict__ xout,
               int e, int last) {
    __shared__ __bf16 s_out[16 * 136];
    __shared__ float sB[192], sC[192];
    const int row = blockIdx.x, tid = threadIdx.x;
    const __bf16* bc = dbcd_bf + (size_t)row * 1920;
    for (int i = tid; i < 192; i += 128) {
        const int l = i >> 4, s = i & 15;
        sB[i] = (float)bc[l * 160 + s];
        sC[i] = (float)bc[l * 160 + 16 + s];
    }
    float As[16];
#pragma unroll
    for (int s = 0; s < 16; ++s) As[s] = -__expf(A_log[e * 16 + s]);
#pragma unroll
    for (int r = 12; r < 16; ++r) s_out[r * 136 + tid] = (__bf16)0.f;
    __syncthreads();

    const float* dmp = dmix + (size_t)row * 1536 + tid;
    const __bf16* xsp = xs_bf + (size_t)row * 1536 + tid;
    const __bf16* szp = sz_bf + (size_t)row * 1536 + tid;
    const __bf16* xfp = xfq_bf + (size_t)row * 1536 + tid;

    float h[16];
#pragma unroll
    for (int s = 0; s < 16; ++s) h[s] = 0.f;
#pragma unroll
    for (int l = 0; l < 12; ++l) {
        const float dl = dmp[l * 128];
        const float xv = (float)xsp[l * 128];
        const float Dp = (float)bc[l * 160 + 32 + tid];
        const float dlx = dl * xv;
        float y = 0.f;
#pragma unroll
        for (int s = 0; s < 16; ++s) {
            h[s] = __expf(dl * As[s]) * h[s] + sB[l * 16 + s] * dlx;
            y += h[s] * sC[l * 16 + s];
        }
        y += Dp * xv;
        const float g = y * (float)szp[l * 128] * (float)xfp[l * 128];
        s_out[l * 136 + tid] = (__bf16)g;
    }
    __syncthreads();

    // out_proj: rows 0..11 (m-tile 16, top 4 rows zero), N=128 split 64/64 by wave
    const int wave = tid >> 6, lane = tid & 63;
    const int lm = lane & 15, lq = lane >> 4;
    const __bf16* Wo = out_w_bf + (size_t)e * 16384;
    bfx8 a[4];
#pragma unroll
    for (int kc = 0; kc < 4; ++kc)
        a[kc] = *(const bfx8*)(s_out + lm * 136 + kc * 32 + lq * 8);

    f32x4 acc[4];
#pragma unroll
    for (int nt = 0; nt < 4; ++nt) acc[nt] = (f32x4){0.f, 0.f, 0.f, 0.f};
#pragma unroll
    for (int kc = 0; kc < 4; ++kc) {
        const int kb = kc * 32 + lq * 8;
#pragma unroll
        for (int nt = 0; nt < 4; ++nt) {
            bfx8 b = *(const bfx8*)(Wo + (size_t)(wave * 64 + nt * 16 + lm) * 128 + kb);
            acc[nt] = MFMA16(a[kc], b, acc[nt]);
        }
    }

    const float bw = blk_w[e], bb = blk_b[e];
#pragma unroll
    for (int nt = 0; nt < 4; ++nt) {
        const int col = wave * 64 + nt * 16 + lm;
        const float ob = out_b[e * 128 + col];
#pragma unroll
        for (int r = 0; r < 4; ++r) {
            const int m = lq * 4 + r;
            if (m < 12) {
                const size_t gi = ((size_t)row * 12 + m) * 128 + col;
                float v = bw * (acc[nt][r] + ob) + bb + xprev[gi];
                if (last) v = fsilu(v);
                xout[gi] = v;
            }
        }
    }
}

extern "C" void kernel_launch(void* const* d_in, const int* in_sizes, int n_in,
                              void* d_out, int out_size, void* d_ws, size_t ws_size,
                              hipStream_t stream) {
    (void)in_sizes; (void)n_in; (void)out_size; (void)ws_size;
    const float* x_in   = (const float*)d_in[0];
    const float* graph  = (const float*)d_in[1];
    const float* in_w   = (const float*)d_in[2];
    const float* in_b   = (const float*)d_in[3];
    const float* x_w    = (const float*)d_in[4];
    const float* dt_w   = (const float*)d_in[5];
    const float* dt_b   = (const float*)d_in[6];
    const float* A_log  = (const float*)d_in[7];
    const float* out_w  = (const float*)d_in[8];
    const float* out_b  = (const float*)d_in[9];
    const float* fw_r   = (const float*)d_in[10];
    const float* fw_i   = (const float*)d_in[11];
    const float* norm_w = (const float*)d_in[12];
    const float* blk_w  = (const float*)d_in[13];
    const float* blk_b  = (const float*)d_in[14];
    float* out = (float*)d_out;

    float* ws = (float*)d_ws;
    size_t o = 0;
    __bf16* in_w_bf   = (__bf16*)(ws + o); o += 131072 / 2;
    __bf16* x_w_bf    = (__bf16*)(ws + o); o += 98304 / 2;
    __bf16* out_w_bf  = (__bf16*)(ws + o); o += 65536 / 2;
    __bf16* dtw_bf    = (__bf16*)(ws + o); o += 65536 / 2;
    __bf16* graphT_bf = (__bf16*)(ws + o); o += 1572864 / 2;
    const size_t NE = (size_t)MROWS * 128;            // 3,772,416 elements
    __bf16* xn_bf    = (__bf16*)(ws + o); o += NE / 2;
    __bf16* xfq_bf   = (__bf16*)(ws + o); o += NE / 2;
    __bf16* xs_bf    = (__bf16*)(ws + o); o += NE / 2;
    __bf16* sz_bf    = (__bf16*)(ws + o); o += NE / 2;
    __bf16* delta_bf = (__bf16*)(ws + o); o += NE / 2;
    __bf16* dbcd_bf  = (__bf16*)(ws + o); o += (size_t)MROWS * 160 / 2;
    float*  dmix     = ws + o;            o += NE;

    hipLaunchKernelGGL(k_convert, dim3(7552), dim3(256), 0, stream,
                       in_w, x_w, out_w, dt_w, graph,
                       in_w_bf, x_w_bf, out_w_bf, dtw_bf, graphT_bf);

    for (int e = 0; e < 4; ++e) {
        const float* xcur = (e == 0) ? x_in : (const float*)out;
        const int last = (e == 3) ? 1 : 0;
        hipLaunchKernelGGL(k_freq, dim3(BN), dim3(128), 0, stream,
                           xcur, norm_w, fw_r, fw_i, xn_bf, xfq_bf, e);
        hipLaunchKernelGGL(gemm_inxp, dim3(614), dim3(384), 0, stream,
                           xn_bf, in_w_bf, in_b, x_w_bf, dtw_bf, dt_b,
                           xs_bf, sz_bf, dbcd_bf, delta_bf, e);
        hipLaunchKernelGGL(gemm_gm, dim3(96, 5, 2), dim3(256), 0, stream,
                           delta_bf, graphT_bf, dmix);
        hipLaunchKernelGGL(k_scanout, dim3(BN), dim3(128), 0, stream,
                           dmix, xs_bf, sz_bf, xfq_bf, dbcd_bf, A_log,
                           out_w_bf, out_b, blk_w, blk_b, xcur, out, e, last);
    }
}

// Round 6
// 504.985 us; speedup vs baseline: 2.1583x; 1.0300x over previous
//
#include <hip/hip_runtime.h>
#include <math.h>

#define BN    2456
#define LSEQ  12
#define DM    128
#define NODES 307
#define MROWS 29472   // BN * LSEQ

typedef __bf16 bfx8 __attribute__((ext_vector_type(8)));
typedef float  f32x4 __attribute__((ext_vector_type(4)));

#define MFMA16(a, b, c) __builtin_amdgcn_mfma_f32_16x16x32_bf16(a, b, c, 0, 0, 0)

__device__ __forceinline__ float fsilu(float v)     { return v / (1.0f + __expf(-v)); }
__device__ __forceinline__ float fsoftplus(float x) { return fmaxf(x, 0.f) + __logf(1.0f + __expf(-fabsf(x))); }

// ---------------- K0: convert weights to bf16 once per call ----------------
__global__ __launch_bounds__(256)
void k_convert(const float* __restrict__ in_w, const float* __restrict__ x_w,
               const float* __restrict__ out_w, const float* __restrict__ dt_w,
               const float* __restrict__ graph,
               __bf16* __restrict__ in_w_bf, __bf16* __restrict__ x_w_bf,
               __bf16* __restrict__ out_w_bf, __bf16* __restrict__ dtw_bf,
               __bf16* __restrict__ graphT_bf) {
    int idx = blockIdx.x * 256 + threadIdx.x;
    if (idx < 131072) { in_w_bf[idx] = (__bf16)in_w[idx]; return; }
    idx -= 131072;
    if (idx < 98304) { x_w_bf[idx] = (__bf16)x_w[idx]; return; }
    idx -= 98304;
    if (idx < 65536) { out_w_bf[idx] = (__bf16)out_w[idx]; return; }
    idx -= 65536;
    if (idx < 65536) { dtw_bf[idx] = (__bf16)dt_w[idx]; return; }
    idx -= 65536;
    if (idx < 1572864) {
        int bl = idx >> 14, r = idx & 16383;
        int d = r >> 7, a = r & 127;
        graphT_bf[(size_t)bl * 16384 + a * 128 + d] = (__bf16)graph[idx];
    }
}

// ---------------- block reductions over 128 threads (2 waves) ----------------
template <int N>
__device__ __forceinline__ void red_sum128(float* v, float* sred, int tid) {
#pragma unroll
    for (int off = 32; off; off >>= 1)
#pragma unroll
        for (int i = 0; i < N; ++i) v[i] += __shfl_xor(v[i], off, 64);
    if ((tid & 63) == 0) {
#pragma unroll
        for (int i = 0; i < N; ++i) sred[(tid >> 6) * N + i] = v[i];
    }
    __syncthreads();
#pragma unroll
    for (int i = 0; i < N; ++i) v[i] = sred[i] + sred[N + i];
    __syncthreads();
}

template <int N>
__device__ __forceinline__ void red_max128(float* v, float* sred, int tid) {
#pragma unroll
    for (int off = 32; off; off >>= 1)
#pragma unroll
        for (int i = 0; i < N; ++i) v[i] = fmaxf(v[i], __shfl_xor(v[i], off, 64));
    if ((tid & 63) == 0) {
#pragma unroll
        for (int i = 0; i < N; ++i) sred[(tid >> 6) * N + i] = v[i];
    }
    __syncthreads();
#pragma unroll
    for (int i = 0; i < N; ++i) v[i] = fmaxf(sred[i], sred[N + i]);
    __syncthreads();
}

// ---------------- shared freq-gating body: input xnr-source in s_res[l*132+d] ----------------
// computes rmsnorm -> xn_bf, and the DFT/topk/softmax gate -> xfq_bf, for expert e.
__device__ __forceinline__
void freq_body(const float* __restrict__ s_res, const float* __restrict__ norm_w,
               const float* __restrict__ fw_r, const float* __restrict__ fw_i,
               float* s_c, float* s_s, float* s_wr, float* s_wi, float* sred,
               __bf16* __restrict__ xn_bf, __bf16* __restrict__ xfq_bf,
               int row, int e, int tid) {
    if (tid < 24) {
        float sv, cv;
        __sincosf(6.283185307179586f * (float)tid / 24.0f, &sv, &cv);
        s_c[tid] = cv; s_s[tid] = sv;
    }
    for (int i = tid; i < 133; i += 128) { s_wr[i] = fw_r[e * 133 + i]; s_wi[i] = fw_i[e * 133 + i]; }

    float xv[12], v[12];
#pragma unroll
    for (int l = 0; l < 12; ++l) { xv[l] = s_res[l * 132 + tid]; v[l] = xv[l] * xv[l]; }
    __syncthreads();
    red_sum128<12>(v, sred, tid);

    const float nw = norm_w[e * DM + tid];
    float xnr[12];
#pragma unroll
    for (int l = 0; l < 12; ++l)
        xnr[l] = xv[l] * rsqrtf(v[l] * (1.0f / 128.0f) + 1e-5f) * nw;

    __bf16* xnp = xn_bf + (size_t)row * (LSEQ * DM) + tid;
#pragma unroll
    for (int l = 0; l < 12; ++l) xnp[l * DM] = (__bf16)xnr[l];

    float fr[7], fi[7], fpr[13], fpi[13];
#pragma unroll
    for (int o2 = 0; o2 < 7; ++o2) { fr[o2] = 0.f; fi[o2] = 0.f; }
#pragma unroll
    for (int k = 0; k < 13; ++k) { fpr[k] = 0.f; fpi[k] = 0.f; }
#pragma unroll
    for (int l = 0; l < 12; ++l) {
#pragma unroll
        for (int o2 = 0; o2 < 7; ++o2) {
            const int t = (2 * o2 * l) % 24;
            fr[o2] += xnr[l] * s_c[t];
            fi[o2] -= xnr[l] * s_s[t];
        }
#pragma unroll
        for (int k = 0; k < 13; ++k) {
            const int t = (k * l) % 24;
            fpr[k] += xnr[l] * s_c[t];
            fpi[k] -= xnr[l] * s_s[t];
        }
    }

    float a7[7];
#pragma unroll
    for (int o2 = 0; o2 < 7; ++o2) {
        float ar = fr[o2] + 1e-6f, ai = fi[o2] + 1e-6f;
        a7[o2] = ar * ar + ai * ai;
    }
#pragma unroll
    for (int pss = 0; pss < 6; ++pss)
#pragma unroll
        for (int j = 0; j < 6; ++j) {
            float hi = fmaxf(a7[j], a7[j + 1]);
            float lo = fminf(a7[j], a7[j + 1]);
            a7[j] = hi; a7[j + 1] = lo;
        }

    float p7[7];
#pragma unroll
    for (int o2 = 0; o2 < 7; ++o2) {
        float pr = 0.f, pi = 0.f;
#pragma unroll
        for (int k = 0; k < 13; ++k) {
            const float wr = s_wr[o2 * 19 + k], wi = s_wi[o2 * 19 + k];
            pr += fpr[k] * wr - fpi[k] * wi;
            pi += fpr[k] * wi + fpi[k] * wr;
        }
#pragma unroll
        for (int k = 0; k < 6; ++k) {
            const float wr = s_wr[o2 * 19 + 13 + k], wi = s_wi[o2 * 19 + 13 + k];
            pr += a7[k] * wr;
            pi += a7[k] * wi;
        }
        p7[o2] = pr * pr + pi * pi;
    }

    float m7[7], ex[7], sm[7];
#pragma unroll
    for (int o2 = 0; o2 < 7; ++o2) m7[o2] = p7[o2];
    red_max128<7>(m7, sred, tid);
#pragma unroll
    for (int o2 = 0; o2 < 7; ++o2) { ex[o2] = __expf(p7[o2] - m7[o2]); sm[o2] = ex[o2]; }
    red_sum128<7>(sm, sred, tid);

    float gr[7], gi[7];
#pragma unroll
    for (int o2 = 0; o2 < 7; ++o2) {
        const float wf = ex[o2] / sm[o2];
        gr[o2] = wf * fr[o2];
        gi[o2] = wf * fi[o2];
    }

    __bf16* xfp = xfq_bf + (size_t)row * (LSEQ * DM) + tid;
#pragma unroll
    for (int l = 0; l < 12; ++l) {
        float val = gr[0] + ((l & 1) ? -gr[6] : gr[6]);
#pragma unroll
        for (int o2 = 1; o2 < 6; ++o2) {
            const int t = (2 * o2 * l) % 24;
            val += 2.0f * (gr[o2] * s_c[t] - gi[o2] * s_s[t]);
        }
        xfp[l * DM] = (__bf16)(val * (1.0f / 12.0f));
    }
}

// ---------------- K1: standalone freq (expert 0 only) ----------------
__global__ __launch_bounds__(128)
void k_freq(const float* __restrict__ xcur, const float* __restrict__ norm_w,
            const float* __restrict__ fw_r, const float* __restrict__ fw_i,
            __bf16* __restrict__ xn_bf, __bf16* __restrict__ xfq_bf, int e) {
    __shared__ float s_res[12 * 132];
    __shared__ float s_c[24], s_s[24], s_wr[133], s_wi[133], sred[24];
    const int row = blockIdx.x, tid = threadIdx.x;
    const float* xp = xcur + (size_t)row * (LSEQ * DM) + tid;
#pragma unroll
    for (int l = 0; l < 12; ++l) s_res[l * 132 + tid] = xp[l * DM];
    __syncthreads();
    freq_body(s_res, norm_w, fw_r, fw_i, s_c, s_s, s_wr, s_wi, sred,
              xn_bf, xfq_bf, row, e, tid);
}

// ---------------- K2: fused in_proj + silu + x_proj + dt_proj ----------------
// grid (1842) x 256 (4 waves). 16 rows/block; n-tiles split across waves.
__global__ __launch_bounds__(256)
void gemm_inxp(const __bf16* __restrict__ xn_bf, const __bf16* __restrict__ in_w_bf,
               const float* __restrict__ in_b, const __bf16* __restrict__ x_w_bf,
               const __bf16* __restrict__ dtw_bf, const float* __restrict__ dt_b,
               __bf16* __restrict__ xs_bf, __bf16* __restrict__ sz_bf,
               __bf16* __restrict__ dbcd_bf, __bf16* __restrict__ delta_bf, int e) {
    __shared__ __bf16 sxs[16 * 136];
    __shared__ __bf16 sdel[16 * 40];
    const int tid = threadIdx.x;
    const int wave = tid >> 6, lane = tid & 63;
    const int lm = lane & 15, lq = lane >> 4;
    const int m0g = blockIdx.x * 16;

    // ---- phase 1: in_proj, 16 n-tiles split 4/wave ----
    const __bf16* Wi = in_w_bf + (size_t)e * 256 * 128;
    bfx8 af[4];
#pragma unroll
    for (int kc = 0; kc < 4; ++kc)
        af[kc] = *(const bfx8*)(xn_bf + (size_t)(m0g + lm) * 128 + kc * 32 + lq * 8);

    f32x4 acc[4];
#pragma unroll
    for (int nt = 0; nt < 4; ++nt) acc[nt] = (f32x4){0.f, 0.f, 0.f, 0.f};
#pragma unroll
    for (int kc = 0; kc < 4; ++kc) {
        const int kb = kc * 32 + lq * 8;
#pragma unroll
        for (int ntl = 0; ntl < 4; ++ntl) {
            bfx8 b = *(const bfx8*)(Wi + (size_t)(wave * 64 + ntl * 16 + lm) * 128 + kb);
            acc[ntl] = MFMA16(af[kc], b, acc[ntl]);
        }
    }
#pragma unroll
    for (int ntl = 0; ntl < 4; ++ntl) {
        const int col = wave * 64 + ntl * 16 + lm;
        const float bias = in_b[e * 256 + col];
#pragma unroll
        for (int r = 0; r < 4; ++r) {
            const int rl = lq * 4 + r;
            const float v = fsilu(acc[ntl][r] + bias);
            if (col < 128) {
                sxs[rl * 136 + col] = (__bf16)v;
                xs_bf[(size_t)(m0g + rl) * 128 + col] = (__bf16)v;
            } else {
                sz_bf[(size_t)(m0g + rl) * 128 + (col - 128)] = (__bf16)v;
            }
        }
    }
    __syncthreads();

    // ---- phase 2: x_proj, 12 n-tiles split 3/wave, A from LDS ----
    const __bf16* Wx = x_w_bf + (size_t)e * 192 * 128;
    bfx8 ax[4];
#pragma unroll
    for (int kc = 0; kc < 4; ++kc)
        ax[kc] = *(const bfx8*)(sxs + lm * 136 + kc * 32 + lq * 8);

    f32x4 xacc[3];
#pragma unroll
    for (int nt = 0; nt < 3; ++nt) xacc[nt] = (f32x4){0.f, 0.f, 0.f, 0.f};
#pragma unroll
    for (int kc = 0; kc < 4; ++kc) {
        const int kb = kc * 32 + lq * 8;
#pragma unroll
        for (int ntl = 0; ntl < 3; ++ntl) {
            bfx8 b = *(const bfx8*)(Wx + (size_t)((wave * 3 + ntl) * 16 + lm) * 128 + kb);
            xacc[ntl] = MFMA16(ax[kc], b, xacc[ntl]);
        }
    }
#pragma unroll
    for (int ntl = 0; ntl < 3; ++ntl) {
        const int col = (wave * 3 + ntl) * 16 + lm;
#pragma unroll
        for (int r = 0; r < 4; ++r) {
            const int rl = lq * 4 + r;
            const float v = xacc[ntl][r];
            if (col < 32) sdel[rl * 40 + col] = (__bf16)v;
            else dbcd_bf[(size_t)(m0g + rl) * 160 + (col - 32)] = (__bf16)v;
        }
    }
    __syncthreads();

    // ---- phase 3: dt projection (K=32), 8 n-tiles split 2/wave ----
    const __bf16* DW = dtw_bf + (size_t)e * 128 * 32;
    bfx8 ad = *(const bfx8*)(sdel + lm * 40 + lq * 8);
    const f32x4 z4 = {0.f, 0.f, 0.f, 0.f};
#pragma unroll
    for (int ntl = 0; ntl < 2; ++ntl) {
        const int nt = wave * 2 + ntl;
        bfx8 b = *(const bfx8*)(DW + (size_t)(nt * 16 + lm) * 32 + lq * 8);
        f32x4 dacc = MFMA16(ad, b, z4);
        const int col = nt * 16 + lm;
        const float bias = dt_b[e * 128 + col];
#pragma unroll
        for (int r = 0; r < 4; ++r) {
            const int m = m0g + lq * 4 + r;
            delta_bf[(size_t)m * 128 + col] = (__bf16)fsoftplus(dacc[r] + bias);
        }
    }
}

// ---------------- K3: graph mixing, 96 batched MFMA GEMMs -> dmix f32 ----------------
__global__ __launch_bounds__(256)
void gemm_gm(const __bf16* __restrict__ delta_bf, const __bf16* __restrict__ graphT_bf,
             float* __restrict__ dmix) {
    const int bl = blockIdx.x;
    const int b = bl / 12, l = bl - b * 12;
    const int tid = threadIdx.x;
    const int wave = tid >> 6, lane = tid & 63;
    const int lm = lane & 15, lq = lane >> 4;
    const int nbase = blockIdx.y * 64 + wave * 16;
    const int n0c = blockIdx.z * 64;
    const __bf16* Bp = graphT_bf + (size_t)bl * 16384;

    f32x4 acc[4];
#pragma unroll
    for (int nt = 0; nt < 4; ++nt) acc[nt] = (f32x4){0.f, 0.f, 0.f, 0.f};

    const int nodeA = min(nbase + lm, NODES - 1);
    const __bf16* Ap = delta_bf + ((size_t)(b * NODES + nodeA) * 12 + l) * 128;

#pragma unroll
    for (int kc = 0; kc < 4; ++kc) {
        const int kb = kc * 32 + lq * 8;
        bfx8 a = *(const bfx8*)(Ap + kb);
#pragma unroll
        for (int nt = 0; nt < 4; ++nt) {
            bfx8 bb = *(const bfx8*)(Bp + (size_t)(n0c + nt * 16 + lm) * 128 + kb);
            acc[nt] = MFMA16(a, bb, acc[nt]);
        }
    }

#pragma unroll
    for (int nt = 0; nt < 4; ++nt)
#pragma unroll
        for (int r = 0; r < 4; ++r) {
            const int node = nbase + lq * 4 + r;
            if (node < NODES)
                dmix[((size_t)(b * NODES + node) * 12 + l) * 128 + n0c + nt * 16 + lm] = acc[nt][r];
        }
}

// ---------------- K4: SSM scan + gate + out_proj + residual + next-expert freq ----------------
// grid (2456) x 128
__global__ __launch_bounds__(128)
void k_scanout(const float* __restrict__ dmix, const __bf16* __restrict__ xs_bf,
               const __bf16* __restrict__ sz_bf, const __bf16* __restrict__ xfq_bf,
               const __bf16* __restrict__ dbcd_bf, const float* __restrict__ A_log,
               const __bf16* __restrict__ out_w_bf, const float* __restrict__ out_b,
               const float* __restrict__ blk_w, const float* __restrict__ blk_b,
               const float* __restrict__ xprev, float* __restrict__ xout,
               const float* __restrict__ norm_w, const float* __restrict__ fw_r,
               const float* __restrict__ fw_i, __bf16* __restrict__ xn_bf,
               __bf16* __restrict__ xfq_out, int e, int last) {
    __shared__ __bf16 s_out[16 * 136];
    __shared__ float sB[192], sC[192];
    __shared__ float s_res[12 * 132];
    __shared__ float s_c[24], s_s[24], s_wr[133], s_wi[133], sred[24];
    const int row = blockIdx.x, tid = threadIdx.x;
    const __bf16* bc = dbcd_bf + (size_t)row * 1920;
    for (int i = tid; i < 192; i += 128) {
        const int l = i >> 4, s = i & 15;
        sB[i] = (float)bc[l * 160 + s];
        sC[i] = (float)bc[l * 160 + 16 + s];
    }
    float As[16];
#pragma unroll
    for (int s = 0; s < 16; ++s) As[s] = -__expf(A_log[e * 16 + s]);
#pragma unroll
    for (int r = 12; r < 16; ++r) s_out[r * 136 + tid] = (__bf16)0.f;
    __syncthreads();

    const float* dmp = dmix + (size_t)row * 1536 + tid;
    const __bf16* xsp = xs_bf + (size_t)row * 1536 + tid;
    const __bf16* szp = sz_bf + (size_t)row * 1536 + tid;
    const __bf16* xfp = xfq_bf + (size_t)row * 1536 + tid;

    float h[16];
#pragma unroll
    for (int s = 0; s < 16; ++s) h[s] = 0.f;
#pragma unroll
    for (int l = 0; l < 12; ++l) {
        const float dl = dmp[l * 128];
        const float xv = (float)xsp[l * 128];
        const float Dp = (float)bc[l * 160 + 32 + tid];
        const float dlx = dl * xv;
        float y = 0.f;
#pragma unroll
        for (int s = 0; s < 16; ++s) {
            h[s] = __expf(dl * As[s]) * h[s] + sB[l * 16 + s] * dlx;
            y += h[s] * sC[l * 16 + s];
        }
        y += Dp * xv;
        const float g = y * (float)szp[l * 128] * (float)xfp[l * 128];
        s_out[l * 136 + tid] = (__bf16)g;
    }
    __syncthreads();

    // out_proj: N=128 split 64/64 by wave
    const int wave = tid >> 6, lane = tid & 63;
    const int lm = lane & 15, lq = lane >> 4;
    const __bf16* Wo = out_w_bf + (size_t)e * 16384;
    bfx8 a[4];
#pragma unroll
    for (int kc = 0; kc < 4; ++kc)
        a[kc] = *(const bfx8*)(s_out + lm * 136 + kc * 32 + lq * 8);

    f32x4 acc[4];
#pragma unroll
    for (int nt = 0; nt < 4; ++nt) acc[nt] = (f32x4){0.f, 0.f, 0.f, 0.f};
#pragma unroll
    for (int kc = 0; kc < 4; ++kc) {
        const int kb = kc * 32 + lq * 8;
#pragma unroll
        for (int nt = 0; nt < 4; ++nt) {
            bfx8 b = *(const bfx8*)(Wo + (size_t)(wave * 64 + nt * 16 + lm) * 128 + kb);
            acc[nt] = MFMA16(a[kc], b, acc[nt]);
        }
    }

    const float bw = blk_w[e], bb = blk_b[e];
#pragma unroll
    for (int nt = 0; nt < 4; ++nt) {
        const int col = wave * 64 + nt * 16 + lm;
        const float ob = out_b[e * 128 + col];
#pragma unroll
        for (int r = 0; r < 4; ++r) {
            const int m = lq * 4 + r;
            if (m < 12) {
                const size_t gi = ((size_t)row * 12 + m) * 128 + col;
                float v = bw * (acc[nt][r] + ob) + bb + xprev[gi];
                if (last) v = fsilu(v);
                xout[gi] = v;
                s_res[m * 132 + col] = v;
            }
        }
    }

    if (!last) {
        __syncthreads();
        freq_body(s_res, norm_w, fw_r, fw_i, s_c, s_s, s_wr, s_wi, sred,
                  xn_bf, xfq_out, row, e + 1, tid);
    }
}

extern "C" void kernel_launch(void* const* d_in, const int* in_sizes, int n_in,
                              void* d_out, int out_size, void* d_ws, size_t ws_size,
                              hipStream_t stream) {
    (void)in_sizes; (void)n_in; (void)out_size; (void)ws_size;
    const float* x_in   = (const float*)d_in[0];
    const float* graph  = (const float*)d_in[1];
    const float* in_w   = (const float*)d_in[2];
    const float* in_b   = (const float*)d_in[3];
    const float* x_w    = (const float*)d_in[4];
    const float* dt_w   = (const float*)d_in[5];
    const float* dt_b   = (const float*)d_in[6];
    const float* A_log  = (const float*)d_in[7];
    const float* out_w  = (const float*)d_in[8];
    const float* out_b  = (const float*)d_in[9];
    const float* fw_r   = (const float*)d_in[10];
    const float* fw_i   = (const float*)d_in[11];
    const float* norm_w = (const float*)d_in[12];
    const float* blk_w  = (const float*)d_in[13];
    const float* blk_b  = (const float*)d_in[14];
    float* out = (float*)d_out;

    float* ws = (float*)d_ws;
    size_t o = 0;
    __bf16* in_w_bf   = (__bf16*)(ws + o); o += 131072 / 2;
    __bf16* x_w_bf    = (__bf16*)(ws + o); o += 98304 / 2;
    __bf16* out_w_bf  = (__bf16*)(ws + o); o += 65536 / 2;
    __bf16* dtw_bf    = (__bf16*)(ws + o); o += 65536 / 2;
    __bf16* graphT_bf = (__bf16*)(ws + o); o += 1572864 / 2;
    const size_t NE = (size_t)MROWS * 128;            // 3,772,416 elements
    __bf16* xn_bf    = (__bf16*)(ws + o); o += NE / 2;
    __bf16* xfq_bf   = (__bf16*)(ws + o); o += NE / 2;
    __bf16* xs_bf    = (__bf16*)(ws + o); o += NE / 2;
    __bf16* sz_bf    = (__bf16*)(ws + o); o += NE / 2;
    __bf16* delta_bf = (__bf16*)(ws + o); o += NE / 2;
    __bf16* dbcd_bf  = (__bf16*)(ws + o); o += (size_t)MROWS * 160 / 2;
    float*  dmix     = ws + o;            o += NE;

    hipLaunchKernelGGL(k_convert, dim3(7552), dim3(256), 0, stream,
                       in_w, x_w, out_w, dt_w, graph,
                       in_w_bf, x_w_bf, out_w_bf, dtw_bf, graphT_bf);

    hipLaunchKernelGGL(k_freq, dim3(BN), dim3(128), 0, stream,
                       x_in, norm_w, fw_r, fw_i, xn_bf, xfq_bf, 0);

    for (int e = 0; e < 4; ++e) {
        const float* xcur = (e == 0) ? x_in : (const float*)out;
        const int last = (e == 3) ? 1 : 0;
        hipLaunchKernelGGL(gemm_inxp, dim3(1842), dim3(256), 0, stream,
                           xn_bf, in_w_bf, in_b, x_w_bf, dtw_bf, dt_b,
                           xs_bf, sz_bf, dbcd_bf, delta_bf, e);
        hipLaunchKernelGGL(gemm_gm, dim3(96, 5, 2), dim3(256), 0, stream,
                           delta_bf, graphT_bf, dmix);
        hipLaunchKernelGGL(k_scanout, dim3(BN), dim3(128), 0, stream,
                           dmix, xs_bf, sz_bf, xfq_bf, dbcd_bf, A_log,
                           out_w_bf, out_b, blk_w, blk_b, xcur, out,
                           norm_w, fw_r, fw_i, xn_bf, xfq_bf, e, last);
    }
}